// Round 1
// baseline (308.751 us; speedup 1.0000x reference)
//
#include <hip/hip_runtime.h>

#define B_ 4
#define N_ 1024
#define E_ 512
#define H_ 8
#define D_ 64
#define BH_ 32

typedef __bf16 bf16;
typedef __bf16 bf16x8 __attribute__((ext_vector_type(8)));
typedef float f32x4 __attribute__((ext_vector_type(4)));

// ---------- prep: fp32 -> bf16 hi (+ optional lo) ----------
__global__ void prep_hilo(const float* __restrict__ src, bf16* __restrict__ hi,
                          bf16* __restrict__ lo, int n) {
    int i = blockIdx.x * blockDim.x + threadIdx.x;
    if (i < n) {
        float x = src[i];
        bf16 h = (bf16)x;
        hi[i] = h;
        if (lo) lo[i] = (bf16)(x - (float)h);
    }
}

// ---------- Q/K projection: y = X @ W^T + b, split-bf16 (3-term), hi/lo out ----------
// Out layout: [B*H][N][D]
__global__ __launch_bounds__(256) void qk_gemm(
    const bf16* __restrict__ Xh, const bf16* __restrict__ Xl,
    const bf16* __restrict__ Wh, const bf16* __restrict__ Wl,
    const float* __restrict__ bias,
    bf16* __restrict__ Oh, bf16* __restrict__ Ol)
{
    const int e0 = blockIdx.x * 64;
    const int m0 = blockIdx.y * 64;
    const int tid = threadIdx.x;
    const int w = tid >> 6, l = tid & 63, lr = l & 15, lg = l >> 4;

    f32x4 acc[4] = {};
    const bf16* xh = &Xh[(size_t)(m0 + w * 16 + lr) * E_];
    const bf16* xl = &Xl[(size_t)(m0 + w * 16 + lr) * E_];

    for (int k0 = 0; k0 < E_; k0 += 32) {
        bf16x8 ah = *(const bf16x8*)(xh + k0 + lg * 8);
        bf16x8 al = *(const bf16x8*)(xl + k0 + lg * 8);
#pragma unroll
        for (int t = 0; t < 4; ++t) {
            const bf16* wh = &Wh[(size_t)(e0 + 16 * t + lr) * E_ + k0 + lg * 8];
            const bf16* wl = &Wl[(size_t)(e0 + 16 * t + lr) * E_ + k0 + lg * 8];
            bf16x8 bh = *(const bf16x8*)wh;
            bf16x8 bl = *(const bf16x8*)wl;
            acc[t] = __builtin_amdgcn_mfma_f32_16x16x32_bf16(ah, bh, acc[t], 0, 0, 0);
            acc[t] = __builtin_amdgcn_mfma_f32_16x16x32_bf16(al, bh, acc[t], 0, 0, 0);
            acc[t] = __builtin_amdgcn_mfma_f32_16x16x32_bf16(ah, bl, acc[t], 0, 0, 0);
        }
    }

    const int h = e0 >> 6;
#pragma unroll
    for (int t = 0; t < 4; ++t) {
        float bv = bias[e0 + 16 * t + lr];
#pragma unroll
        for (int r = 0; r < 4; ++r) {
            int m = m0 + w * 16 + lg * 4 + r;
            int b = m >> 10, n = m & (N_ - 1);
            int d = 16 * t + lr;
            float v = acc[t][r] + bv;
            bf16 hi = (bf16)v;
            size_t idx = ((size_t)(b * H_ + h) * N_ + n) * D_ + d;
            Oh[idx] = hi;
            Ol[idx] = (bf16)(v - (float)hi);
        }
    }
}

// ---------- V projection: plain bf16, output TRANSPOSED [B*H][D][N] ----------
__global__ __launch_bounds__(256) void v_gemm(
    const bf16* __restrict__ Xh,
    const bf16* __restrict__ Wh,
    const float* __restrict__ bias,
    bf16* __restrict__ Vt)
{
    __shared__ alignas(16) bf16 lds[64 * 72];
    const int e0 = blockIdx.x * 64;
    const int m0 = blockIdx.y * 64;
    const int tid = threadIdx.x;
    const int w = tid >> 6, l = tid & 63, lr = l & 15, lg = l >> 4;

    f32x4 acc[4] = {};
    const bf16* xh = &Xh[(size_t)(m0 + w * 16 + lr) * E_];

    for (int k0 = 0; k0 < E_; k0 += 32) {
        bf16x8 ah = *(const bf16x8*)(xh + k0 + lg * 8);
#pragma unroll
        for (int t = 0; t < 4; ++t) {
            bf16x8 bh = *(const bf16x8*)(&Wh[(size_t)(e0 + 16 * t + lr) * E_ + k0 + lg * 8]);
            acc[t] = __builtin_amdgcn_mfma_f32_16x16x32_bf16(ah, bh, acc[t], 0, 0, 0);
        }
    }

    // write tile transposed into LDS: lds[d_local][n_local]
#pragma unroll
    for (int t = 0; t < 4; ++t) {
        float bv = bias[e0 + 16 * t + lr];
#pragma unroll
        for (int r = 0; r < 4; ++r) {
            lds[(16 * t + lr) * 72 + w * 16 + lg * 4 + r] = (bf16)(acc[t][r] + bv);
        }
    }
    __syncthreads();

    // each thread writes 16 contiguous n for one d
    int d = tid >> 2, c0 = (tid & 3) * 16;
    int b = m0 >> 10, n = (m0 & (N_ - 1)) + c0, h = e0 >> 6;
    bf16x8* dst = (bf16x8*)&Vt[((size_t)(b * H_ + h) * D_ + d) * N_ + n];
    const bf16x8* s = (const bf16x8*)&lds[d * 72 + c0];
    dst[0] = s[0];
    dst[1] = s[1];
}

// ---------- fused attention (flash-style, online softmax) ----------
// Q,K split hi/lo (6-MFMA QK^T); P,V plain bf16. Each wave: 16 q-rows.
__global__ __launch_bounds__(256) void attn_kernel(
    const bf16* __restrict__ Qh, const bf16* __restrict__ Ql,
    const bf16* __restrict__ Kh, const bf16* __restrict__ Kl,
    const bf16* __restrict__ Vt,
    const float* __restrict__ rn,
    const float* __restrict__ addm, const float* __restrict__ multm,
    bf16* __restrict__ AOh, bf16* __restrict__ AOl)
{
    __shared__ alignas(16) bf16 plds[4][16 * 72];
    const int bh = blockIdx.y, b = bh >> 3, h = bh & 7;
    const int tid = threadIdx.x;
    const int w = tid >> 6, l = tid & 63, lr = l & 15, lg = l >> 4;
    const int q0 = blockIdx.x * 64 + w * 16;
    bf16* pl = &plds[w][0];

    const bf16* qb = &Qh[((size_t)bh * N_ + q0 + lr) * D_];
    const bf16* qlb = &Ql[((size_t)bh * N_ + q0 + lr) * D_];
    bf16x8 qh0 = *(const bf16x8*)(qb + lg * 8);
    bf16x8 qh1 = *(const bf16x8*)(qb + 32 + lg * 8);
    bf16x8 ql0 = *(const bf16x8*)(qlb + lg * 8);
    bf16x8 ql1 = *(const bf16x8*)(qlb + 32 + lg * 8);

    float rnr[4];
#pragma unroll
    for (int r = 0; r < 4; ++r) rnr[r] = rn[b * N_ + q0 + lg * 4 + r] * 0.125f;

    float mrun[4], lrun[4];
#pragma unroll
    for (int r = 0; r < 4; ++r) { mrun[r] = -3e38f; lrun[r] = 0.f; }
    f32x4 acc[4] = {};

    const float* addb = addm + (size_t)bh * N_ * N_;
    const float* mulb = multm + (size_t)bh * N_ * N_;

    for (int kv0 = 0; kv0 < N_; kv0 += 64) {
        // ---- S = (Q K^T) with hi/lo split ----
        f32x4 s[4];
#pragma unroll
        for (int t = 0; t < 4; ++t) {
            const bf16* kb = &Kh[((size_t)bh * N_ + kv0 + 16 * t + lr) * D_];
            const bf16* klb = &Kl[((size_t)bh * N_ + kv0 + 16 * t + lr) * D_];
            bf16x8 kh0 = *(const bf16x8*)(kb + lg * 8);
            bf16x8 kh1 = *(const bf16x8*)(kb + 32 + lg * 8);
            bf16x8 kl0 = *(const bf16x8*)(klb + lg * 8);
            bf16x8 kl1 = *(const bf16x8*)(klb + 32 + lg * 8);
            f32x4 z = {};
            z = __builtin_amdgcn_mfma_f32_16x16x32_bf16(qh0, kh0, z, 0, 0, 0);
            z = __builtin_amdgcn_mfma_f32_16x16x32_bf16(qh1, kh1, z, 0, 0, 0);
            z = __builtin_amdgcn_mfma_f32_16x16x32_bf16(ql0, kh0, z, 0, 0, 0);
            z = __builtin_amdgcn_mfma_f32_16x16x32_bf16(ql1, kh1, z, 0, 0, 0);
            z = __builtin_amdgcn_mfma_f32_16x16x32_bf16(qh0, kl0, z, 0, 0, 0);
            z = __builtin_amdgcn_mfma_f32_16x16x32_bf16(qh1, kl1, z, 0, 0, 0);
            s[t] = z;
        }
        // ---- scale by real_nodes/sqrt(D), add mask ----
        float sv[4][4];
#pragma unroll
        for (int t = 0; t < 4; ++t) {
#pragma unroll
            for (int r = 0; r < 4; ++r) {
                size_t q = (size_t)(q0 + lg * 4 + r);
                sv[t][r] = s[t][r] * rnr[r] + addb[q * N_ + kv0 + 16 * t + lr];
            }
        }
        // ---- online softmax (row = 16-lane group, 4 col-tiles) ----
        float pv[4][4];
#pragma unroll
        for (int r = 0; r < 4; ++r) {
            float v = fmaxf(fmaxf(sv[0][r], sv[1][r]), fmaxf(sv[2][r], sv[3][r]));
            v = fmaxf(v, __shfl_xor(v, 1));
            v = fmaxf(v, __shfl_xor(v, 2));
            v = fmaxf(v, __shfl_xor(v, 4));
            v = fmaxf(v, __shfl_xor(v, 8));
            float mn = fmaxf(mrun[r], v);
            float rs = __expf(mrun[r] - mn);
            mrun[r] = mn;
            lrun[r] *= rs;
#pragma unroll
            for (int t = 0; t < 4; ++t) acc[t][r] *= rs;
            float rsum = 0.f;
#pragma unroll
            for (int t = 0; t < 4; ++t) { pv[t][r] = __expf(sv[t][r] - mn); rsum += pv[t][r]; }
            rsum += __shfl_xor(rsum, 1);
            rsum += __shfl_xor(rsum, 2);
            rsum += __shfl_xor(rsum, 4);
            rsum += __shfl_xor(rsum, 8);
            lrun[r] += rsum;
        }
        // ---- P_eff = exp * mult -> bf16 -> LDS (layout fix for A-fragment) ----
#pragma unroll
        for (int t = 0; t < 4; ++t) {
#pragma unroll
            for (int r = 0; r < 4; ++r) {
                size_t q = (size_t)(q0 + lg * 4 + r);
                float mu = mulb[q * N_ + kv0 + 16 * t + lr];
                pl[(lg * 4 + r) * 72 + 16 * t + lr] = (bf16)(pv[t][r] * mu);
            }
        }
        // ---- O += P_eff @ V ----
        bf16x8 pa0 = *(const bf16x8*)(pl + lr * 72 + lg * 8);
        bf16x8 pa1 = *(const bf16x8*)(pl + lr * 72 + 32 + lg * 8);
#pragma unroll
        for (int t = 0; t < 4; ++t) {
            const bf16* vb = &Vt[((size_t)bh * D_ + 16 * t + lr) * N_ + kv0];
            bf16x8 vb0 = *(const bf16x8*)(vb + lg * 8);
            bf16x8 vb1 = *(const bf16x8*)(vb + 32 + lg * 8);
            acc[t] = __builtin_amdgcn_mfma_f32_16x16x32_bf16(pa0, vb0, acc[t], 0, 0, 0);
            acc[t] = __builtin_amdgcn_mfma_f32_16x16x32_bf16(pa1, vb1, acc[t], 0, 0, 0);
        }
    }

    // ---- normalize, store attention output (hi/lo) to [B][N][E] ----
#pragma unroll
    for (int t = 0; t < 4; ++t) {
#pragma unroll
        for (int r = 0; r < 4; ++r) {
            int q = q0 + lg * 4 + r;
            int d = 16 * t + lr;
            float o = acc[t][r] / lrun[r];
            size_t idx = ((size_t)b * N_ + q) * E_ + h * D_ + d;
            bf16 hi = (bf16)o;
            AOh[idx] = hi;
            AOl[idx] = (bf16)(o - (float)hi);
        }
    }
}

// ---------- output projection: split-bf16 (3-term), fp32 out + bias ----------
__global__ __launch_bounds__(256) void out_gemm(
    const bf16* __restrict__ Ah, const bf16* __restrict__ Al,
    const bf16* __restrict__ Wh, const bf16* __restrict__ Wl,
    const float* __restrict__ bias,
    float* __restrict__ out)
{
    const int e0 = blockIdx.x * 64;
    const int m0 = blockIdx.y * 64;
    const int tid = threadIdx.x;
    const int w = tid >> 6, l = tid & 63, lr = l & 15, lg = l >> 4;

    f32x4 acc[4] = {};
    const bf16* ah_p = &Ah[(size_t)(m0 + w * 16 + lr) * E_];
    const bf16* al_p = &Al[(size_t)(m0 + w * 16 + lr) * E_];

    for (int k0 = 0; k0 < E_; k0 += 32) {
        bf16x8 ah = *(const bf16x8*)(ah_p + k0 + lg * 8);
        bf16x8 al = *(const bf16x8*)(al_p + k0 + lg * 8);
#pragma unroll
        for (int t = 0; t < 4; ++t) {
            bf16x8 bh = *(const bf16x8*)(&Wh[(size_t)(e0 + 16 * t + lr) * E_ + k0 + lg * 8]);
            bf16x8 bl = *(const bf16x8*)(&Wl[(size_t)(e0 + 16 * t + lr) * E_ + k0 + lg * 8]);
            acc[t] = __builtin_amdgcn_mfma_f32_16x16x32_bf16(ah, bh, acc[t], 0, 0, 0);
            acc[t] = __builtin_amdgcn_mfma_f32_16x16x32_bf16(al, bh, acc[t], 0, 0, 0);
            acc[t] = __builtin_amdgcn_mfma_f32_16x16x32_bf16(ah, bl, acc[t], 0, 0, 0);
        }
    }

#pragma unroll
    for (int t = 0; t < 4; ++t) {
        float bv = bias[e0 + 16 * t + lr];
#pragma unroll
        for (int r = 0; r < 4; ++r) {
            int m = m0 + w * 16 + lg * 4 + r;
            out[(size_t)m * E_ + e0 + 16 * t + lr] = acc[t][r] + bv;
        }
    }
}

extern "C" void kernel_launch(void* const* d_in, const int* in_sizes, int n_in,
                              void* d_out, int out_size, void* d_ws, size_t ws_size,
                              hipStream_t stream) {
    const float* X = (const float*)d_in[0];
    const float* rn = (const float*)d_in[1];
    const float* addm = (const float*)d_in[2];
    const float* multm = (const float*)d_in[3];
    const float* Wq = (const float*)d_in[4];
    const float* bq = (const float*)d_in[5];
    const float* Wk = (const float*)d_in[6];
    const float* bk = (const float*)d_in[7];
    const float* Wv = (const float*)d_in[8];
    const float* bv = (const float*)d_in[9];
    const float* Wo = (const float*)d_in[10];
    const float* bo = (const float*)d_in[11];
    float* out = (float*)d_out;

    const size_t SZ_X = (size_t)B_ * N_ * E_;  // 2M elems
    const size_t SZ_W = (size_t)E_ * E_;       // 256K elems

    bf16* p = (bf16*)d_ws;
    bf16* Xh = p;  p += SZ_X;
    bf16* Xl = p;  p += SZ_X;
    bf16* Wqh = p; p += SZ_W;
    bf16* Wql = p; p += SZ_W;
    bf16* Wkh = p; p += SZ_W;
    bf16* Wkl = p; p += SZ_W;
    bf16* Wvh = p; p += SZ_W;
    bf16* Woh = p; p += SZ_W;
    bf16* Wol = p; p += SZ_W;
    bf16* Qh = p;  p += SZ_X;
    bf16* Ql = p;  p += SZ_X;
    bf16* Kh = p;  p += SZ_X;
    bf16* Kl = p;  p += SZ_X;
    bf16* Vt = p;  p += SZ_X;
    bf16* AOh = p; p += SZ_X;
    bf16* AOl = p; p += SZ_X;

    prep_hilo<<<dim3((int)((SZ_X + 255) / 256)), 256, 0, stream>>>(X, Xh, Xl, (int)SZ_X);
    prep_hilo<<<dim3((int)((SZ_W + 255) / 256)), 256, 0, stream>>>(Wq, Wqh, Wql, (int)SZ_W);
    prep_hilo<<<dim3((int)((SZ_W + 255) / 256)), 256, 0, stream>>>(Wk, Wkh, Wkl, (int)SZ_W);
    prep_hilo<<<dim3((int)((SZ_W + 255) / 256)), 256, 0, stream>>>(Wv, Wvh, nullptr, (int)SZ_W);
    prep_hilo<<<dim3((int)((SZ_W + 255) / 256)), 256, 0, stream>>>(Wo, Woh, Wol, (int)SZ_W);

    dim3 gg(E_ / 64, (B_ * N_) / 64);  // (8, 64)
    qk_gemm<<<gg, 256, 0, stream>>>(Xh, Xl, Wqh, Wql, bq, Qh, Ql);
    qk_gemm<<<gg, 256, 0, stream>>>(Xh, Xl, Wkh, Wkl, bk, Kh, Kl);
    v_gemm<<<gg, 256, 0, stream>>>(Xh, Wvh, bv, Vt);

    attn_kernel<<<dim3(N_ / 64, BH_), 256, 0, stream>>>(Qh, Ql, Kh, Kl, Vt, rn, addm, multm, AOh, AOl);

    out_gemm<<<gg, 256, 0, stream>>>(AOh, AOl, Woh, Wol, bo, out);
}

// Round 2
// 294.174 us; speedup vs baseline: 1.0496x; 1.0496x over previous
//
#include <hip/hip_runtime.h>

#define B_ 4
#define N_ 1024
#define E_ 512
#define H_ 8
#define D_ 64
#define BH_ 32

typedef __bf16 bf16;
typedef __bf16 bf16x8 __attribute__((ext_vector_type(8)));
typedef __bf16 bf16x4 __attribute__((ext_vector_type(4)));
typedef float f32x4 __attribute__((ext_vector_type(4)));

// ---------- prep: all fp32 -> bf16 hi/lo conversions in one launch ----------
__global__ __launch_bounds__(256) void prep_all(
    const float* __restrict__ X, const float* __restrict__ Wq,
    const float* __restrict__ Wk, const float* __restrict__ Wv,
    const float* __restrict__ Wo,
    bf16* __restrict__ Xh, bf16* __restrict__ Xl,
    bf16* __restrict__ Wqh, bf16* __restrict__ Wql,
    bf16* __restrict__ Wkh, bf16* __restrict__ Wkl,
    bf16* __restrict__ Wvh,
    bf16* __restrict__ Woh, bf16* __restrict__ Wol)
{
    const int NX = B_ * N_ * E_;   // 2M
    const int NW = E_ * E_;        // 256K
    int i = blockIdx.x * 256 + threadIdx.x;
    if (i < NX) {
        float x = X[i]; bf16 h = (bf16)x;
        Xh[i] = h; Xl[i] = (bf16)(x - (float)h);
        return;
    }
    i -= NX;
    int w = i >> 18, j = i & (NW - 1);
    if (w == 0) { float x = Wq[j]; bf16 h = (bf16)x; Wqh[j] = h; Wql[j] = (bf16)(x - (float)h); }
    else if (w == 1) { float x = Wk[j]; bf16 h = (bf16)x; Wkh[j] = h; Wkl[j] = (bf16)(x - (float)h); }
    else if (w == 2) { float x = Wv[j]; Wvh[j] = (bf16)x; }
    else if (w == 3) { float x = Wo[j]; bf16 h = (bf16)x; Woh[j] = h; Wol[j] = (bf16)(x - (float)h); }
}

// ---------- Q/K projection: y = X @ W^T + b, split-bf16 (3-term), hi/lo out ----------
// Out layout: [B*H][N][D]
__global__ __launch_bounds__(256) void qk_gemm(
    const bf16* __restrict__ Xh, const bf16* __restrict__ Xl,
    const bf16* __restrict__ Wh, const bf16* __restrict__ Wl,
    const float* __restrict__ bias,
    bf16* __restrict__ Oh, bf16* __restrict__ Ol)
{
    const int e0 = blockIdx.x * 64;
    const int m0 = blockIdx.y * 64;
    const int tid = threadIdx.x;
    const int w = tid >> 6, l = tid & 63, lr = l & 15, lg = l >> 4;

    f32x4 acc[4] = {};
    const bf16* xh = &Xh[(size_t)(m0 + w * 16 + lr) * E_];
    const bf16* xl = &Xl[(size_t)(m0 + w * 16 + lr) * E_];

    for (int k0 = 0; k0 < E_; k0 += 32) {
        bf16x8 ah = *(const bf16x8*)(xh + k0 + lg * 8);
        bf16x8 al = *(const bf16x8*)(xl + k0 + lg * 8);
#pragma unroll
        for (int t = 0; t < 4; ++t) {
            const bf16* wh = &Wh[(size_t)(e0 + 16 * t + lr) * E_ + k0 + lg * 8];
            const bf16* wl = &Wl[(size_t)(e0 + 16 * t + lr) * E_ + k0 + lg * 8];
            bf16x8 bh = *(const bf16x8*)wh;
            bf16x8 bl = *(const bf16x8*)wl;
            acc[t] = __builtin_amdgcn_mfma_f32_16x16x32_bf16(ah, bh, acc[t], 0, 0, 0);
            acc[t] = __builtin_amdgcn_mfma_f32_16x16x32_bf16(al, bh, acc[t], 0, 0, 0);
            acc[t] = __builtin_amdgcn_mfma_f32_16x16x32_bf16(ah, bl, acc[t], 0, 0, 0);
        }
    }

    const int h = e0 >> 6;
#pragma unroll
    for (int t = 0; t < 4; ++t) {
        float bv = bias[e0 + 16 * t + lr];
#pragma unroll
        for (int r = 0; r < 4; ++r) {
            int m = m0 + w * 16 + lg * 4 + r;
            int b = m >> 10, n = m & (N_ - 1);
            int d = 16 * t + lr;
            float v = acc[t][r] + bv;
            bf16 hi = (bf16)v;
            size_t idx = ((size_t)(b * H_ + h) * N_ + n) * D_ + d;
            Oh[idx] = hi;
            Ol[idx] = (bf16)(v - (float)hi);
        }
    }
}

// ---------- V projection: plain bf16, output TRANSPOSED [B*H][D][N] ----------
__global__ __launch_bounds__(256) void v_gemm(
    const bf16* __restrict__ Xh,
    const bf16* __restrict__ Wh,
    const float* __restrict__ bias,
    bf16* __restrict__ Vt)
{
    __shared__ alignas(16) bf16 lds[64 * 72];
    const int e0 = blockIdx.x * 64;
    const int m0 = blockIdx.y * 64;
    const int tid = threadIdx.x;
    const int w = tid >> 6, l = tid & 63, lr = l & 15, lg = l >> 4;

    f32x4 acc[4] = {};
    const bf16* xh = &Xh[(size_t)(m0 + w * 16 + lr) * E_];

    for (int k0 = 0; k0 < E_; k0 += 32) {
        bf16x8 ah = *(const bf16x8*)(xh + k0 + lg * 8);
#pragma unroll
        for (int t = 0; t < 4; ++t) {
            bf16x8 bh = *(const bf16x8*)(&Wh[(size_t)(e0 + 16 * t + lr) * E_ + k0 + lg * 8]);
            acc[t] = __builtin_amdgcn_mfma_f32_16x16x32_bf16(ah, bh, acc[t], 0, 0, 0);
        }
    }

    // write tile transposed into LDS: lds[d_local][n_local]
#pragma unroll
    for (int t = 0; t < 4; ++t) {
        float bv = bias[e0 + 16 * t + lr];
#pragma unroll
        for (int r = 0; r < 4; ++r) {
            lds[(16 * t + lr) * 72 + w * 16 + lg * 4 + r] = (bf16)(acc[t][r] + bv);
        }
    }
    __syncthreads();

    // each thread writes 16 contiguous n for one d
    int d = tid >> 2, c0 = (tid & 3) * 16;
    int b = m0 >> 10, n = (m0 & (N_ - 1)) + c0, h = e0 >> 6;
    bf16x8* dst = (bf16x8*)&Vt[((size_t)(b * H_ + h) * D_ + d) * N_ + n];
    const bf16x8* s = (const bf16x8*)&lds[d * 72 + c0];
    dst[0] = s[0];
    dst[1] = s[1];
}

// ---------- fused attention, KV-split flash with unnormalized partials ----------
// grid: (N_/64, ks*BH_). Each block: 64 q-rows x one KV chunk of N_/ks.
// Writes Opart (unnormalized), Mb, Lb for the merge kernel.
__global__ __launch_bounds__(256, 4) void attn_kernel(
    const bf16* __restrict__ Qh, const bf16* __restrict__ Ql,
    const bf16* __restrict__ Kh, const bf16* __restrict__ Kl,
    const bf16* __restrict__ Vt,
    const float* __restrict__ rn,
    const float* __restrict__ addm, const float* __restrict__ multm,
    float* __restrict__ Opart, float* __restrict__ Mb, float* __restrict__ Lb,
    int ch)
{
    __shared__ alignas(16) bf16 plds[4][16 * 72];
    const int by = blockIdx.y;
    const int bh = by & (BH_ - 1), c = by >> 5;
    const int b = bh >> 3;
    const int kvb = c * ch;
    const int tid = threadIdx.x;
    const int w = tid >> 6, l = tid & 63, lr = l & 15, lg = l >> 4;
    const int q0 = blockIdx.x * 64 + w * 16;
    bf16* pl = &plds[w][0];

    const bf16* qb = &Qh[((size_t)bh * N_ + q0 + lr) * D_];
    const bf16* qlb = &Ql[((size_t)bh * N_ + q0 + lr) * D_];
    bf16x8 qh0 = *(const bf16x8*)(qb + lg * 8);
    bf16x8 qh1 = *(const bf16x8*)(qb + 32 + lg * 8);
    bf16x8 ql0 = *(const bf16x8*)(qlb + lg * 8);
    bf16x8 ql1 = *(const bf16x8*)(qlb + 32 + lg * 8);

    float rnr[4];
#pragma unroll
    for (int r = 0; r < 4; ++r) rnr[r] = rn[b * N_ + q0 + lg * 4 + r] * 0.125f;

    float mrun[4], lrun[4];
#pragma unroll
    for (int r = 0; r < 4; ++r) { mrun[r] = -3e38f; lrun[r] = 0.f; }
    f32x4 acc[4] = {};

    const float* addb = addm + (size_t)bh * N_ * N_;
    const float* mulb = multm + (size_t)bh * N_ * N_;

    for (int kv0 = kvb; kv0 < kvb + ch; kv0 += 64) {
        // ---- prefetch BOTH masks into registers first (latency hidden by QK^T) ----
        float madd[4][4], mmul[4][4];
#pragma unroll
        for (int t = 0; t < 4; ++t) {
#pragma unroll
            for (int r = 0; r < 4; ++r) {
                size_t q = (size_t)(q0 + lg * 4 + r);
                madd[t][r] = addb[q * N_ + kv0 + 16 * t + lr];
                mmul[t][r] = mulb[q * N_ + kv0 + 16 * t + lr];
            }
        }
        // ---- S = (Q K^T) with hi/lo split ----
        f32x4 s[4];
#pragma unroll
        for (int t = 0; t < 4; ++t) {
            const bf16* kb = &Kh[((size_t)bh * N_ + kv0 + 16 * t + lr) * D_];
            const bf16* klb = &Kl[((size_t)bh * N_ + kv0 + 16 * t + lr) * D_];
            bf16x8 kh0 = *(const bf16x8*)(kb + lg * 8);
            bf16x8 kh1 = *(const bf16x8*)(kb + 32 + lg * 8);
            bf16x8 kl0 = *(const bf16x8*)(klb + lg * 8);
            bf16x8 kl1 = *(const bf16x8*)(klb + 32 + lg * 8);
            f32x4 z = {};
            z = __builtin_amdgcn_mfma_f32_16x16x32_bf16(qh0, kh0, z, 0, 0, 0);
            z = __builtin_amdgcn_mfma_f32_16x16x32_bf16(qh1, kh1, z, 0, 0, 0);
            z = __builtin_amdgcn_mfma_f32_16x16x32_bf16(ql0, kh0, z, 0, 0, 0);
            z = __builtin_amdgcn_mfma_f32_16x16x32_bf16(ql1, kh1, z, 0, 0, 0);
            z = __builtin_amdgcn_mfma_f32_16x16x32_bf16(qh0, kl0, z, 0, 0, 0);
            z = __builtin_amdgcn_mfma_f32_16x16x32_bf16(qh1, kl1, z, 0, 0, 0);
            s[t] = z;
        }
        // ---- scale by real_nodes/sqrt(D), add mask ----
        float sv[4][4];
#pragma unroll
        for (int t = 0; t < 4; ++t) {
#pragma unroll
            for (int r = 0; r < 4; ++r)
                sv[t][r] = s[t][r] * rnr[r] + madd[t][r];
        }
        // ---- online softmax (row = 16-lane group, 4 col-tiles) ----
        float pv[4][4];
#pragma unroll
        for (int r = 0; r < 4; ++r) {
            float v = fmaxf(fmaxf(sv[0][r], sv[1][r]), fmaxf(sv[2][r], sv[3][r]));
            v = fmaxf(v, __shfl_xor(v, 1));
            v = fmaxf(v, __shfl_xor(v, 2));
            v = fmaxf(v, __shfl_xor(v, 4));
            v = fmaxf(v, __shfl_xor(v, 8));
            float mn = fmaxf(mrun[r], v);
            float rs = __expf(mrun[r] - mn);
            mrun[r] = mn;
            lrun[r] *= rs;
#pragma unroll
            for (int t = 0; t < 4; ++t) acc[t][r] *= rs;
            float rsum = 0.f;
#pragma unroll
            for (int t = 0; t < 4; ++t) { pv[t][r] = __expf(sv[t][r] - mn); rsum += pv[t][r]; }
            rsum += __shfl_xor(rsum, 1);
            rsum += __shfl_xor(rsum, 2);
            rsum += __shfl_xor(rsum, 4);
            rsum += __shfl_xor(rsum, 8);
            lrun[r] += rsum;
        }
        // ---- P_eff = exp * mult -> bf16 -> LDS (layout fix for A-fragment) ----
#pragma unroll
        for (int t = 0; t < 4; ++t) {
#pragma unroll
            for (int r = 0; r < 4; ++r) {
                pl[(lg * 4 + r) * 72 + 16 * t + lr] = (bf16)(pv[t][r] * mmul[t][r]);
            }
        }
        // ---- O += P_eff @ V ----
        bf16x8 pa0 = *(const bf16x8*)(pl + lr * 72 + lg * 8);
        bf16x8 pa1 = *(const bf16x8*)(pl + lr * 72 + 32 + lg * 8);
#pragma unroll
        for (int t = 0; t < 4; ++t) {
            const bf16* vb = &Vt[((size_t)bh * D_ + 16 * t + lr) * N_ + kv0];
            bf16x8 vb0 = *(const bf16x8*)(vb + lg * 8);
            bf16x8 vb1 = *(const bf16x8*)(vb + 32 + lg * 8);
            acc[t] = __builtin_amdgcn_mfma_f32_16x16x32_bf16(pa0, vb0, acc[t], 0, 0, 0);
            acc[t] = __builtin_amdgcn_mfma_f32_16x16x32_bf16(pa1, vb1, acc[t], 0, 0, 0);
        }
    }

    // ---- store unnormalized partials ----
    const size_t cb = ((size_t)c * BH_ + bh) * N_;
#pragma unroll
    for (int t = 0; t < 4; ++t) {
#pragma unroll
        for (int r = 0; r < 4; ++r) {
            int q = q0 + lg * 4 + r;
            Opart[(cb + q) * D_ + 16 * t + lr] = acc[t][r];
        }
    }
    if (lr == 0) {
#pragma unroll
        for (int r = 0; r < 4; ++r) {
            int q = q0 + lg * 4 + r;
            Mb[cb + q] = mrun[r];
            Lb[cb + q] = lrun[r];
        }
    }
}

// ---------- merge KV-split partials -> normalized attention out (hi/lo bf16) ----------
__global__ __launch_bounds__(256) void merge_kernel(
    const float* __restrict__ Opart, const float* __restrict__ Mb,
    const float* __restrict__ Lb,
    bf16* __restrict__ AOh, bf16* __restrict__ AOl, int ks)
{
    int idx = blockIdx.x * 256 + threadIdx.x;   // BH*N*(D/4) = 512K
    int bh = idx >> 14;
    int rem = idx & 16383;
    int q = rem >> 4, d4 = rem & 15;

    float M = -3e38f;
    for (int c = 0; c < ks; ++c)
        M = fmaxf(M, Mb[((size_t)c * BH_ + bh) * N_ + q]);
    float L = 0.f;
    f32x4 o = {};
    for (int c = 0; c < ks; ++c) {
        size_t base = ((size_t)c * BH_ + bh) * N_ + q;
        float wgt = __expf(Mb[base] - M);
        L += wgt * Lb[base];
        f32x4 v = *(const f32x4*)&Opart[base * D_ + d4 * 4];
        o += wgt * v;
    }
    float inv = 1.f / L;
    int b = bh >> 3, h = bh & 7;
    size_t ob = ((size_t)b * N_ + q) * E_ + h * D_ + d4 * 4;
    bf16x4 hi, lo;
#pragma unroll
    for (int j = 0; j < 4; ++j) {
        float x = o[j] * inv;
        bf16 hh = (bf16)x;
        hi[j] = hh;
        lo[j] = (bf16)(x - (float)hh);
    }
    *(bf16x4*)&AOh[ob] = hi;
    *(bf16x4*)&AOl[ob] = lo;
}

// ---------- output projection: split-bf16 (3-term), fp32 out + bias ----------
__global__ __launch_bounds__(256) void out_gemm(
    const bf16* __restrict__ Ah, const bf16* __restrict__ Al,
    const bf16* __restrict__ Wh, const bf16* __restrict__ Wl,
    const float* __restrict__ bias,
    float* __restrict__ out)
{
    const int e0 = blockIdx.x * 64;
    const int m0 = blockIdx.y * 64;
    const int tid = threadIdx.x;
    const int w = tid >> 6, l = tid & 63, lr = l & 15, lg = l >> 4;

    f32x4 acc[4] = {};
    const bf16* ah_p = &Ah[(size_t)(m0 + w * 16 + lr) * E_];
    const bf16* al_p = &Al[(size_t)(m0 + w * 16 + lr) * E_];

    for (int k0 = 0; k0 < E_; k0 += 32) {
        bf16x8 ah = *(const bf16x8*)(ah_p + k0 + lg * 8);
        bf16x8 al = *(const bf16x8*)(al_p + k0 + lg * 8);
#pragma unroll
        for (int t = 0; t < 4; ++t) {
            bf16x8 bh = *(const bf16x8*)(&Wh[(size_t)(e0 + 16 * t + lr) * E_ + k0 + lg * 8]);
            bf16x8 bl = *(const bf16x8*)(&Wl[(size_t)(e0 + 16 * t + lr) * E_ + k0 + lg * 8]);
            acc[t] = __builtin_amdgcn_mfma_f32_16x16x32_bf16(ah, bh, acc[t], 0, 0, 0);
            acc[t] = __builtin_amdgcn_mfma_f32_16x16x32_bf16(al, bh, acc[t], 0, 0, 0);
            acc[t] = __builtin_amdgcn_mfma_f32_16x16x32_bf16(ah, bl, acc[t], 0, 0, 0);
        }
    }

#pragma unroll
    for (int t = 0; t < 4; ++t) {
        float bv = bias[e0 + 16 * t + lr];
#pragma unroll
        for (int r = 0; r < 4; ++r) {
            int m = m0 + w * 16 + lg * 4 + r;
            out[(size_t)m * E_ + e0 + 16 * t + lr] = acc[t][r] + bv;
        }
    }
}

extern "C" void kernel_launch(void* const* d_in, const int* in_sizes, int n_in,
                              void* d_out, int out_size, void* d_ws, size_t ws_size,
                              hipStream_t stream) {
    const float* X = (const float*)d_in[0];
    const float* rn = (const float*)d_in[1];
    const float* addm = (const float*)d_in[2];
    const float* multm = (const float*)d_in[3];
    const float* Wq = (const float*)d_in[4];
    const float* bq = (const float*)d_in[5];
    const float* Wk = (const float*)d_in[6];
    const float* bk = (const float*)d_in[7];
    const float* Wv = (const float*)d_in[8];
    const float* bv = (const float*)d_in[9];
    const float* Wo = (const float*)d_in[10];
    const float* bo = (const float*)d_in[11];
    float* out = (float*)d_out;

    const size_t SZ_X = (size_t)B_ * N_ * E_;  // 2M elems
    const size_t SZ_W = (size_t)E_ * E_;       // 256K elems

    bf16* p = (bf16*)d_ws;
    bf16* Xh = p;  p += SZ_X;
    bf16* Xl = p;  p += SZ_X;
    bf16* Wqh = p; p += SZ_W;
    bf16* Wql = p; p += SZ_W;
    bf16* Wkh = p; p += SZ_W;
    bf16* Wkl = p; p += SZ_W;
    bf16* Wvh = p; p += SZ_W;
    bf16* Woh = p; p += SZ_W;
    bf16* Wol = p; p += SZ_W;
    bf16* Qh = p;  p += SZ_X;
    bf16* Ql = p;  p += SZ_X;
    bf16* Kh = p;  p += SZ_X;
    bf16* Kl = p;  p += SZ_X;
    bf16* Vt = p;  p += SZ_X;
    bf16* AOh = p; p += SZ_X;
    bf16* AOl = p; p += SZ_X;

    // KV-split factor chosen by workspace budget
    size_t fixed_bytes = (size_t)((char*)p - (char*)d_ws);
    size_t per_ks = (size_t)BH_ * N_ * D_ * 4 + (size_t)BH_ * N_ * 2 * 4;
    int ks = 4;
    if (fixed_bytes + 4 * per_ks > ws_size) ks = 2;
    if (fixed_bytes + 2 * per_ks > ws_size) ks = 1;

    float* Opart = (float*)p;
    float* Mb = Opart + (size_t)ks * BH_ * N_ * D_;
    float* Lb = Mb + (size_t)ks * BH_ * N_;

    const int NPREP = B_ * N_ * E_ + 4 * E_ * E_;  // 3M+
    prep_all<<<dim3(NPREP / 256), 256, 0, stream>>>(X, Wq, Wk, Wv, Wo,
        Xh, Xl, Wqh, Wql, Wkh, Wkl, Wvh, Woh, Wol);

    dim3 gg(E_ / 64, (B_ * N_) / 64);  // (8, 64)
    qk_gemm<<<gg, 256, 0, stream>>>(Xh, Xl, Wqh, Wql, bq, Qh, Ql);
    qk_gemm<<<gg, 256, 0, stream>>>(Xh, Xl, Wkh, Wkl, bk, Kh, Kl);
    v_gemm<<<gg, 256, 0, stream>>>(Xh, Wvh, bv, Vt);

    attn_kernel<<<dim3(N_ / 64, ks * BH_), 256, 0, stream>>>(
        Qh, Ql, Kh, Kl, Vt, rn, addm, multm, Opart, Mb, Lb, N_ / ks);

    merge_kernel<<<dim3((BH_ * N_ * (D_ / 4)) / 256), 256, 0, stream>>>(
        Opart, Mb, Lb, AOh, AOl, ks);

    out_gemm<<<gg, 256, 0, stream>>>(AOh, AOl, Woh, Wol, bo, out);
}

// Round 3
// 270.354 us; speedup vs baseline: 1.1420x; 1.0881x over previous
//
#include <hip/hip_runtime.h>

#define B_ 4
#define N_ 1024
#define E_ 512
#define H_ 8
#define D_ 64
#define BH_ 32

typedef __bf16 bf16;
typedef __bf16 bf16x8 __attribute__((ext_vector_type(8)));
typedef __bf16 bf16x4 __attribute__((ext_vector_type(4)));
typedef float f32x4 __attribute__((ext_vector_type(4)));

// ---------- prep: all fp32 -> bf16 hi/lo conversions in one launch ----------
__global__ __launch_bounds__(256) void prep_all(
    const float* __restrict__ X, const float* __restrict__ Wq,
    const float* __restrict__ Wk, const float* __restrict__ Wv,
    const float* __restrict__ Wo,
    bf16* __restrict__ Xh, bf16* __restrict__ Xl,
    bf16* __restrict__ Wqh, bf16* __restrict__ Wql,
    bf16* __restrict__ Wkh, bf16* __restrict__ Wkl,
    bf16* __restrict__ Wvh,
    bf16* __restrict__ Woh, bf16* __restrict__ Wol)
{
    const int NX = B_ * N_ * E_;   // 2M
    const int NW = E_ * E_;        // 256K
    int i = blockIdx.x * 256 + threadIdx.x;
    if (i < NX) {
        float x = X[i]; bf16 h = (bf16)x;
        Xh[i] = h; Xl[i] = (bf16)(x - (float)h);
        return;
    }
    i -= NX;
    int w = i >> 18, j = i & (NW - 1);
    if (w == 0) { float x = Wq[j]; bf16 h = (bf16)x; Wqh[j] = h; Wql[j] = (bf16)(x - (float)h); }
    else if (w == 1) { float x = Wk[j]; bf16 h = (bf16)x; Wkh[j] = h; Wkl[j] = (bf16)(x - (float)h); }
    else if (w == 2) { float x = Wv[j]; Wvh[j] = (bf16)x; }
    else if (w == 3) { float x = Wo[j]; bf16 h = (bf16)x; Woh[j] = h; Wol[j] = (bf16)(x - (float)h); }
}

// ---------- Q/K projection: y = X @ W^T + b, split-bf16 (3-term), hi/lo out ----------
// Out layout: [B*H][N][D]
__global__ __launch_bounds__(256) void qk_gemm(
    const bf16* __restrict__ Xh, const bf16* __restrict__ Xl,
    const bf16* __restrict__ Wh, const bf16* __restrict__ Wl,
    const float* __restrict__ bias,
    bf16* __restrict__ Oh, bf16* __restrict__ Ol)
{
    const int e0 = blockIdx.x * 64;
    const int m0 = blockIdx.y * 64;
    const int tid = threadIdx.x;
    const int w = tid >> 6, l = tid & 63, lr = l & 15, lg = l >> 4;

    f32x4 acc[4] = {};
    const bf16* xh = &Xh[(size_t)(m0 + w * 16 + lr) * E_];
    const bf16* xl = &Xl[(size_t)(m0 + w * 16 + lr) * E_];

    for (int k0 = 0; k0 < E_; k0 += 32) {
        bf16x8 ah = *(const bf16x8*)(xh + k0 + lg * 8);
        bf16x8 al = *(const bf16x8*)(xl + k0 + lg * 8);
#pragma unroll
        for (int t = 0; t < 4; ++t) {
            const bf16* wh = &Wh[(size_t)(e0 + 16 * t + lr) * E_ + k0 + lg * 8];
            const bf16* wl = &Wl[(size_t)(e0 + 16 * t + lr) * E_ + k0 + lg * 8];
            bf16x8 bh = *(const bf16x8*)wh;
            bf16x8 bl = *(const bf16x8*)wl;
            acc[t] = __builtin_amdgcn_mfma_f32_16x16x32_bf16(ah, bh, acc[t], 0, 0, 0);
            acc[t] = __builtin_amdgcn_mfma_f32_16x16x32_bf16(al, bh, acc[t], 0, 0, 0);
            acc[t] = __builtin_amdgcn_mfma_f32_16x16x32_bf16(ah, bl, acc[t], 0, 0, 0);
        }
    }

    const int h = e0 >> 6;
#pragma unroll
    for (int t = 0; t < 4; ++t) {
        float bv = bias[e0 + 16 * t + lr];
#pragma unroll
        for (int r = 0; r < 4; ++r) {
            int m = m0 + w * 16 + lg * 4 + r;
            int b = m >> 10, n = m & (N_ - 1);
            int d = 16 * t + lr;
            float v = acc[t][r] + bv;
            bf16 hi = (bf16)v;
            size_t idx = ((size_t)(b * H_ + h) * N_ + n) * D_ + d;
            Oh[idx] = hi;
            Ol[idx] = (bf16)(v - (float)hi);
        }
    }
}

// ---------- V projection: plain bf16, output TRANSPOSED [B*H][D][N] ----------
__global__ __launch_bounds__(256) void v_gemm(
    const bf16* __restrict__ Xh,
    const bf16* __restrict__ Wh,
    const float* __restrict__ bias,
    bf16* __restrict__ Vt)
{
    __shared__ alignas(16) bf16 lds[64 * 72];
    const int e0 = blockIdx.x * 64;
    const int m0 = blockIdx.y * 64;
    const int tid = threadIdx.x;
    const int w = tid >> 6, l = tid & 63, lr = l & 15, lg = l >> 4;

    f32x4 acc[4] = {};
    const bf16* xh = &Xh[(size_t)(m0 + w * 16 + lr) * E_];

    for (int k0 = 0; k0 < E_; k0 += 32) {
        bf16x8 ah = *(const bf16x8*)(xh + k0 + lg * 8);
#pragma unroll
        for (int t = 0; t < 4; ++t) {
            bf16x8 bh = *(const bf16x8*)(&Wh[(size_t)(e0 + 16 * t + lr) * E_ + k0 + lg * 8]);
            acc[t] = __builtin_amdgcn_mfma_f32_16x16x32_bf16(ah, bh, acc[t], 0, 0, 0);
        }
    }

    // write tile transposed into LDS: lds[d_local][n_local]
#pragma unroll
    for (int t = 0; t < 4; ++t) {
        float bv = bias[e0 + 16 * t + lr];
#pragma unroll
        for (int r = 0; r < 4; ++r) {
            lds[(16 * t + lr) * 72 + w * 16 + lg * 4 + r] = (bf16)(acc[t][r] + bv);
        }
    }
    __syncthreads();

    // each thread writes 16 contiguous n for one d
    int d = tid >> 2, c0 = (tid & 3) * 16;
    int b = m0 >> 10, n = (m0 & (N_ - 1)) + c0, h = e0 >> 6;
    bf16x8* dst = (bf16x8*)&Vt[((size_t)(b * H_ + h) * D_ + d) * N_ + n];
    const bf16x8* s = (const bf16x8*)&lds[d * 72 + c0];
    dst[0] = s[0];
    dst[1] = s[1];
}

// ---------- fused attention, KV-split flash with unnormalized partials ----------
// grid: (N_/64, ks*BH_). Each block: 64 q-rows x one KV chunk of N_/ks.
// launch_bounds(256,2): 256-VGPR budget so the 32 in-flight mask loads
// stay register-resident (the (256,4)/64-VGPR build serialized them).
__global__ __launch_bounds__(256, 2) void attn_kernel(
    const bf16* __restrict__ Qh, const bf16* __restrict__ Ql,
    const bf16* __restrict__ Kh, const bf16* __restrict__ Kl,
    const bf16* __restrict__ Vt,
    const float* __restrict__ rn,
    const float* __restrict__ addm, const float* __restrict__ multm,
    float* __restrict__ Opart, float* __restrict__ Mb, float* __restrict__ Lb,
    int ch)
{
    __shared__ alignas(16) bf16 plds[4][16 * 72];
    const int by = blockIdx.y;
    const int bh = by & (BH_ - 1), c = by >> 5;
    const int b = bh >> 3;
    const int kvb = c * ch;
    const int tid = threadIdx.x;
    const int w = tid >> 6, l = tid & 63, lr = l & 15, lg = l >> 4;
    const int q0 = blockIdx.x * 64 + w * 16;
    bf16* pl = &plds[w][0];

    const bf16* qb = &Qh[((size_t)bh * N_ + q0 + lr) * D_];
    const bf16* qlb = &Ql[((size_t)bh * N_ + q0 + lr) * D_];
    bf16x8 qh0 = *(const bf16x8*)(qb + lg * 8);
    bf16x8 qh1 = *(const bf16x8*)(qb + 32 + lg * 8);
    bf16x8 ql0 = *(const bf16x8*)(qlb + lg * 8);
    bf16x8 ql1 = *(const bf16x8*)(qlb + 32 + lg * 8);

    float rnr[4];
#pragma unroll
    for (int r = 0; r < 4; ++r) rnr[r] = rn[b * N_ + q0 + lg * 4 + r] * 0.125f;

    float mrun[4], lrun[4];
#pragma unroll
    for (int r = 0; r < 4; ++r) { mrun[r] = -3e38f; lrun[r] = 0.f; }
    f32x4 acc[4] = {};

    // per-lane mask row pointers (row = q, col offset = lr)
    const size_t mb0 = (size_t)bh * N_ * N_;
    const float* ap[4];
    const float* mp[4];
#pragma unroll
    for (int r = 0; r < 4; ++r) {
        size_t q = (size_t)(q0 + lg * 4 + r);
        ap[r] = addm + mb0 + q * N_ + lr;
        mp[r] = multm + mb0 + q * N_ + lr;
    }

    for (int kv0 = kvb; kv0 < kvb + ch; kv0 += 64) {
        // ---- issue ALL 32 mask loads first; pin them above everything else ----
        float madd[4][4], mmul[4][4];
#pragma unroll
        for (int t = 0; t < 4; ++t) {
#pragma unroll
            for (int r = 0; r < 4; ++r) {
                madd[t][r] = ap[r][kv0 + 16 * t];
                mmul[t][r] = mp[r][kv0 + 16 * t];
            }
        }
        __builtin_amdgcn_sched_barrier(0);

        // ---- S = (Q K^T) with hi/lo split (mask latency hides under this) ----
        f32x4 s[4];
#pragma unroll
        for (int t = 0; t < 4; ++t) {
            const bf16* kb = &Kh[((size_t)bh * N_ + kv0 + 16 * t + lr) * D_];
            const bf16* klb = &Kl[((size_t)bh * N_ + kv0 + 16 * t + lr) * D_];
            bf16x8 kh0 = *(const bf16x8*)(kb + lg * 8);
            bf16x8 kh1 = *(const bf16x8*)(kb + 32 + lg * 8);
            bf16x8 kl0 = *(const bf16x8*)(klb + lg * 8);
            bf16x8 kl1 = *(const bf16x8*)(klb + 32 + lg * 8);
            f32x4 z = {};
            z = __builtin_amdgcn_mfma_f32_16x16x32_bf16(qh0, kh0, z, 0, 0, 0);
            z = __builtin_amdgcn_mfma_f32_16x16x32_bf16(qh1, kh1, z, 0, 0, 0);
            z = __builtin_amdgcn_mfma_f32_16x16x32_bf16(ql0, kh0, z, 0, 0, 0);
            z = __builtin_amdgcn_mfma_f32_16x16x32_bf16(ql1, kh1, z, 0, 0, 0);
            z = __builtin_amdgcn_mfma_f32_16x16x32_bf16(qh0, kl0, z, 0, 0, 0);
            z = __builtin_amdgcn_mfma_f32_16x16x32_bf16(qh1, kl1, z, 0, 0, 0);
            s[t] = z;
        }
        // ---- scale by real_nodes/sqrt(D), add mask ----
        float sv[4][4];
#pragma unroll
        for (int t = 0; t < 4; ++t) {
#pragma unroll
            for (int r = 0; r < 4; ++r)
                sv[t][r] = s[t][r] * rnr[r] + madd[t][r];
        }
        // ---- online softmax (row = 16-lane group, 4 col-tiles) ----
        float pv[4][4];
#pragma unroll
        for (int r = 0; r < 4; ++r) {
            float v = fmaxf(fmaxf(sv[0][r], sv[1][r]), fmaxf(sv[2][r], sv[3][r]));
            v = fmaxf(v, __shfl_xor(v, 1));
            v = fmaxf(v, __shfl_xor(v, 2));
            v = fmaxf(v, __shfl_xor(v, 4));
            v = fmaxf(v, __shfl_xor(v, 8));
            float mn = fmaxf(mrun[r], v);
            float rs = __expf(mrun[r] - mn);
            mrun[r] = mn;
            lrun[r] *= rs;
#pragma unroll
            for (int t = 0; t < 4; ++t) acc[t][r] *= rs;
            float rsum = 0.f;
#pragma unroll
            for (int t = 0; t < 4; ++t) { pv[t][r] = __expf(sv[t][r] - mn); rsum += pv[t][r]; }
            rsum += __shfl_xor(rsum, 1);
            rsum += __shfl_xor(rsum, 2);
            rsum += __shfl_xor(rsum, 4);
            rsum += __shfl_xor(rsum, 8);
            lrun[r] += rsum;
        }
        // ---- P_eff = exp * mult -> bf16 -> LDS (layout fix for A-fragment) ----
#pragma unroll
        for (int t = 0; t < 4; ++t) {
#pragma unroll
            for (int r = 0; r < 4; ++r) {
                pl[(lg * 4 + r) * 72 + 16 * t + lr] = (bf16)(pv[t][r] * mmul[t][r]);
            }
        }
        // ---- O += P_eff @ V ----
        bf16x8 pa0 = *(const bf16x8*)(pl + lr * 72 + lg * 8);
        bf16x8 pa1 = *(const bf16x8*)(pl + lr * 72 + 32 + lg * 8);
#pragma unroll
        for (int t = 0; t < 4; ++t) {
            const bf16* vb = &Vt[((size_t)bh * D_ + 16 * t + lr) * N_ + kv0];
            bf16x8 vb0 = *(const bf16x8*)(vb + lg * 8);
            bf16x8 vb1 = *(const bf16x8*)(vb + 32 + lg * 8);
            acc[t] = __builtin_amdgcn_mfma_f32_16x16x32_bf16(pa0, vb0, acc[t], 0, 0, 0);
            acc[t] = __builtin_amdgcn_mfma_f32_16x16x32_bf16(pa1, vb1, acc[t], 0, 0, 0);
        }
    }

    // ---- store unnormalized partials ----
    const size_t cb = ((size_t)c * BH_ + bh) * N_;
#pragma unroll
    for (int t = 0; t < 4; ++t) {
#pragma unroll
        for (int r = 0; r < 4; ++r) {
            int q = q0 + lg * 4 + r;
            Opart[(cb + q) * D_ + 16 * t + lr] = acc[t][r];
        }
    }
    if (lr == 0) {
#pragma unroll
        for (int r = 0; r < 4; ++r) {
            int q = q0 + lg * 4 + r;
            Mb[cb + q] = mrun[r];
            Lb[cb + q] = lrun[r];
        }
    }
}

// ---------- merge KV-split partials -> normalized attention out (hi/lo bf16) ----------
__global__ __launch_bounds__(256) void merge_kernel(
    const float* __restrict__ Opart, const float* __restrict__ Mb,
    const float* __restrict__ Lb,
    bf16* __restrict__ AOh, bf16* __restrict__ AOl, int ks)
{
    int idx = blockIdx.x * 256 + threadIdx.x;   // BH*N*(D/4) = 512K
    int bh = idx >> 14;
    int rem = idx & 16383;
    int q = rem >> 4, d4 = rem & 15;

    float M = -3e38f;
    for (int c = 0; c < ks; ++c)
        M = fmaxf(M, Mb[((size_t)c * BH_ + bh) * N_ + q]);
    float L = 0.f;
    f32x4 o = {};
    for (int c = 0; c < ks; ++c) {
        size_t base = ((size_t)c * BH_ + bh) * N_ + q;
        float wgt = __expf(Mb[base] - M);
        L += wgt * Lb[base];
        f32x4 v = *(const f32x4*)&Opart[base * D_ + d4 * 4];
        o += wgt * v;
    }
    float inv = 1.f / L;
    int b = bh >> 3, h = bh & 7;
    size_t ob = ((size_t)b * N_ + q) * E_ + h * D_ + d4 * 4;
    bf16x4 hi, lo;
#pragma unroll
    for (int j = 0; j < 4; ++j) {
        float x = o[j] * inv;
        bf16 hh = (bf16)x;
        hi[j] = hh;
        lo[j] = (bf16)(x - (float)hh);
    }
    *(bf16x4*)&AOh[ob] = hi;
    *(bf16x4*)&AOl[ob] = lo;
}

// ---------- output projection: split-bf16 (3-term), fp32 out + bias ----------
__global__ __launch_bounds__(256) void out_gemm(
    const bf16* __restrict__ Ah, const bf16* __restrict__ Al,
    const bf16* __restrict__ Wh, const bf16* __restrict__ Wl,
    const float* __restrict__ bias,
    float* __restrict__ out)
{
    const int e0 = blockIdx.x * 64;
    const int m0 = blockIdx.y * 64;
    const int tid = threadIdx.x;
    const int w = tid >> 6, l = tid & 63, lr = l & 15, lg = l >> 4;

    f32x4 acc[4] = {};
    const bf16* ah_p = &Ah[(size_t)(m0 + w * 16 + lr) * E_];
    const bf16* al_p = &Al[(size_t)(m0 + w * 16 + lr) * E_];

    for (int k0 = 0; k0 < E_; k0 += 32) {
        bf16x8 ah = *(const bf16x8*)(ah_p + k0 + lg * 8);
        bf16x8 al = *(const bf16x8*)(al_p + k0 + lg * 8);
#pragma unroll
        for (int t = 0; t < 4; ++t) {
            bf16x8 bh = *(const bf16x8*)(&Wh[(size_t)(e0 + 16 * t + lr) * E_ + k0 + lg * 8]);
            bf16x8 bl = *(const bf16x8*)(&Wl[(size_t)(e0 + 16 * t + lr) * E_ + k0 + lg * 8]);
            acc[t] = __builtin_amdgcn_mfma_f32_16x16x32_bf16(ah, bh, acc[t], 0, 0, 0);
            acc[t] = __builtin_amdgcn_mfma_f32_16x16x32_bf16(al, bh, acc[t], 0, 0, 0);
            acc[t] = __builtin_amdgcn_mfma_f32_16x16x32_bf16(ah, bl, acc[t], 0, 0, 0);
        }
    }

#pragma unroll
    for (int t = 0; t < 4; ++t) {
        float bv = bias[e0 + 16 * t + lr];
#pragma unroll
        for (int r = 0; r < 4; ++r) {
            int m = m0 + w * 16 + lg * 4 + r;
            out[(size_t)m * E_ + e0 + 16 * t + lr] = acc[t][r] + bv;
        }
    }
}

extern "C" void kernel_launch(void* const* d_in, const int* in_sizes, int n_in,
                              void* d_out, int out_size, void* d_ws, size_t ws_size,
                              hipStream_t stream) {
    const float* X = (const float*)d_in[0];
    const float* rn = (const float*)d_in[1];
    const float* addm = (const float*)d_in[2];
    const float* multm = (const float*)d_in[3];
    const float* Wq = (const float*)d_in[4];
    const float* bq = (const float*)d_in[5];
    const float* Wk = (const float*)d_in[6];
    const float* bk = (const float*)d_in[7];
    const float* Wv = (const float*)d_in[8];
    const float* bv = (const float*)d_in[9];
    const float* Wo = (const float*)d_in[10];
    const float* bo = (const float*)d_in[11];
    float* out = (float*)d_out;

    const size_t SZ_X = (size_t)B_ * N_ * E_;  // 2M elems
    const size_t SZ_W = (size_t)E_ * E_;       // 256K elems

    bf16* p = (bf16*)d_ws;
    bf16* Xh = p;  p += SZ_X;
    bf16* Xl = p;  p += SZ_X;
    bf16* Wqh = p; p += SZ_W;
    bf16* Wql = p; p += SZ_W;
    bf16* Wkh = p; p += SZ_W;
    bf16* Wkl = p; p += SZ_W;
    bf16* Wvh = p; p += SZ_W;
    bf16* Woh = p; p += SZ_W;
    bf16* Wol = p; p += SZ_W;
    bf16* Qh = p;  p += SZ_X;
    bf16* Ql = p;  p += SZ_X;
    bf16* Kh = p;  p += SZ_X;
    bf16* Kl = p;  p += SZ_X;
    bf16* Vt = p;  p += SZ_X;
    bf16* AOh = p; p += SZ_X;
    bf16* AOl = p; p += SZ_X;

    // KV-split factor chosen by workspace budget
    size_t fixed_bytes = (size_t)((char*)p - (char*)d_ws);
    size_t per_ks = (size_t)BH_ * N_ * D_ * 4 + (size_t)BH_ * N_ * 2 * 4;
    int ks = 4;
    if (fixed_bytes + 4 * per_ks > ws_size) ks = 2;
    if (fixed_bytes + 2 * per_ks > ws_size) ks = 1;

    float* Opart = (float*)p;
    float* Mb = Opart + (size_t)ks * BH_ * N_ * D_;
    float* Lb = Mb + (size_t)ks * BH_ * N_;

    const int NPREP = B_ * N_ * E_ + 4 * E_ * E_;  // 3M+
    prep_all<<<dim3(NPREP / 256), 256, 0, stream>>>(X, Wq, Wk, Wv, Wo,
        Xh, Xl, Wqh, Wql, Wkh, Wkl, Wvh, Woh, Wol);

    dim3 gg(E_ / 64, (B_ * N_) / 64);  // (8, 64)
    qk_gemm<<<gg, 256, 0, stream>>>(Xh, Xl, Wqh, Wql, bq, Qh, Ql);
    qk_gemm<<<gg, 256, 0, stream>>>(Xh, Xl, Wkh, Wkl, bk, Kh, Kl);
    v_gemm<<<gg, 256, 0, stream>>>(Xh, Wvh, bv, Vt);

    attn_kernel<<<dim3(N_ / 64, ks * BH_), 256, 0, stream>>>(
        Qh, Ql, Kh, Kl, Vt, rn, addm, multm, Opart, Mb, Lb, N_ / ks);

    merge_kernel<<<dim3((BH_ * N_ * (D_ / 4)) / 256), 256, 0, stream>>>(
        Opart, Mb, Lb, AOh, AOl, ks);

    out_gemm<<<gg, 256, 0, stream>>>(AOh, AOl, Woh, Wol, bo, out);
}

// Round 4
// 268.858 us; speedup vs baseline: 1.1484x; 1.0056x over previous
//
#include <hip/hip_runtime.h>

#define B_ 4
#define N_ 1024
#define E_ 512
#define H_ 8
#define D_ 64
#define BH_ 32
#define KVB 32

typedef __bf16 bf16;
typedef __bf16 bf16x8 __attribute__((ext_vector_type(8)));
typedef __bf16 bf16x4 __attribute__((ext_vector_type(4)));
typedef float f32x4 __attribute__((ext_vector_type(4)));

#define MFMA16 __builtin_amdgcn_mfma_f32_16x16x32_bf16

typedef const __attribute__((address_space(1))) void* gas_t;
typedef __attribute__((address_space(3))) void* las_t;

// global -> LDS direct, 16B/lane, 64 lanes = 1KB per call.
// LDS dest = uniform base + lane*16 (linear); global src is per-lane.
__device__ __forceinline__ void gload16(const float* g, void* l) {
    __builtin_amdgcn_global_load_lds((gas_t)g, (las_t)l, 16, 0, 0);
}

// ---------- prep: all fp32 -> bf16 hi/lo conversions in one launch ----------
__global__ __launch_bounds__(256) void prep_all(
    const float* __restrict__ X, const float* __restrict__ Wq,
    const float* __restrict__ Wk, const float* __restrict__ Wv,
    const float* __restrict__ Wo,
    bf16* __restrict__ Xh, bf16* __restrict__ Xl,
    bf16* __restrict__ Wqh, bf16* __restrict__ Wql,
    bf16* __restrict__ Wkh, bf16* __restrict__ Wkl,
    bf16* __restrict__ Wvh,
    bf16* __restrict__ Woh, bf16* __restrict__ Wol)
{
    const int NX = B_ * N_ * E_;   // 2M
    const int NW = E_ * E_;        // 256K
    int i = blockIdx.x * 256 + threadIdx.x;
    if (i < NX) {
        float x = X[i]; bf16 h = (bf16)x;
        Xh[i] = h; Xl[i] = (bf16)(x - (float)h);
        return;
    }
    i -= NX;
    int w = i >> 18, j = i & (NW - 1);
    if (w == 0) { float x = Wq[j]; bf16 h = (bf16)x; Wqh[j] = h; Wql[j] = (bf16)(x - (float)h); }
    else if (w == 1) { float x = Wk[j]; bf16 h = (bf16)x; Wkh[j] = h; Wkl[j] = (bf16)(x - (float)h); }
    else if (w == 2) { float x = Wv[j]; Wvh[j] = (bf16)x; }
    else if (w == 3) { float x = Wo[j]; bf16 h = (bf16)x; Woh[j] = h; Wol[j] = (bf16)(x - (float)h); }
}

// ---------- fused QKV projection: z=0 -> Q (hi/lo), z=1 -> K (hi/lo), z=2 -> V^T ----------
__global__ __launch_bounds__(256) void qkv_gemm(
    const bf16* __restrict__ Xh, const bf16* __restrict__ Xl,
    const bf16* __restrict__ Wqh, const bf16* __restrict__ Wql, const float* __restrict__ bq,
    const bf16* __restrict__ Wkh, const bf16* __restrict__ Wkl, const float* __restrict__ bk,
    const bf16* __restrict__ Wvh, const float* __restrict__ bvv,
    bf16* __restrict__ Qh, bf16* __restrict__ Ql,
    bf16* __restrict__ Kh, bf16* __restrict__ Kl,
    bf16* __restrict__ Vt)
{
    __shared__ alignas(16) bf16 lds[64 * 72];
    const int z = blockIdx.z;
    const int e0 = blockIdx.x * 64;
    const int m0 = blockIdx.y * 64;
    const int tid = threadIdx.x;
    const int w = tid >> 6, l = tid & 63, lr = l & 15, lg = l >> 4;
    const int h = e0 >> 6;

    const bf16* xh = &Xh[(size_t)(m0 + w * 16 + lr) * E_];

    if (z == 2) {
        // ---- V path: plain bf16, output transposed [B*H][D][N] ----
        f32x4 acc[4] = {};
        for (int k0 = 0; k0 < E_; k0 += 32) {
            bf16x8 ah = *(const bf16x8*)(xh + k0 + lg * 8);
#pragma unroll
            for (int t = 0; t < 4; ++t) {
                bf16x8 bh = *(const bf16x8*)(&Wvh[(size_t)(e0 + 16 * t + lr) * E_ + k0 + lg * 8]);
                acc[t] = MFMA16(ah, bh, acc[t], 0, 0, 0);
            }
        }
#pragma unroll
        for (int t = 0; t < 4; ++t) {
            float bv = bvv[e0 + 16 * t + lr];
#pragma unroll
            for (int r = 0; r < 4; ++r)
                lds[(16 * t + lr) * 72 + w * 16 + lg * 4 + r] = (bf16)(acc[t][r] + bv);
        }
        __syncthreads();
        int d = tid >> 2, c0 = (tid & 3) * 16;
        int b = m0 >> 10, n = (m0 & (N_ - 1)) + c0;
        bf16x8* dst = (bf16x8*)&Vt[((size_t)(b * H_ + h) * D_ + d) * N_ + n];
        const bf16x8* s = (const bf16x8*)&lds[d * 72 + c0];
        dst[0] = s[0];
        dst[1] = s[1];
        return;
    }

    // ---- Q/K path: split-bf16 (3-term), hi/lo out, [B*H][N][D] ----
    const bf16* Wh = z ? Wkh : Wqh;
    const bf16* Wl = z ? Wkl : Wql;
    const float* bias = z ? bk : bq;
    bf16* Oh = z ? Kh : Qh;
    bf16* Ol = z ? Kl : Ql;

    f32x4 acc[4] = {};
    const bf16* xl = &Xl[(size_t)(m0 + w * 16 + lr) * E_];
    for (int k0 = 0; k0 < E_; k0 += 32) {
        bf16x8 ah = *(const bf16x8*)(xh + k0 + lg * 8);
        bf16x8 al = *(const bf16x8*)(xl + k0 + lg * 8);
#pragma unroll
        for (int t = 0; t < 4; ++t) {
            bf16x8 bh = *(const bf16x8*)(&Wh[(size_t)(e0 + 16 * t + lr) * E_ + k0 + lg * 8]);
            bf16x8 bl = *(const bf16x8*)(&Wl[(size_t)(e0 + 16 * t + lr) * E_ + k0 + lg * 8]);
            acc[t] = MFMA16(ah, bh, acc[t], 0, 0, 0);
            acc[t] = MFMA16(al, bh, acc[t], 0, 0, 0);
            acc[t] = MFMA16(ah, bl, acc[t], 0, 0, 0);
        }
    }
#pragma unroll
    for (int t = 0; t < 4; ++t) {
        float bv = bias[e0 + 16 * t + lr];
#pragma unroll
        for (int r = 0; r < 4; ++r) {
            int m = m0 + w * 16 + lg * 4 + r;
            int b = m >> 10, n = m & (N_ - 1);
            float v = acc[t][r] + bv;
            bf16 hi = (bf16)v;
            size_t idx = ((size_t)(b * H_ + h) * N_ + n) * D_ + 16 * t + lr;
            Oh[idx] = hi;
            Ol[idx] = (bf16)(v - (float)hi);
        }
    }
}

// ---------- fused attention, KV-split flash, masks staged via global_load_lds ----------
// grid: (N_/64, ks*BH_). KV tile = 32. Per wave: 16 q-rows; masks double-buffered
// in LDS (4 x 1KB gload_lds per tile, zero VGPR cost), counted vmcnt keeps the
// next tile's mask loads in flight across the current tile's compute.
__global__ __launch_bounds__(256, 2) void attn_kernel(
    const bf16* __restrict__ Qh_, const bf16* __restrict__ Ql_,
    const bf16* __restrict__ Kh_, const bf16* __restrict__ Kl_,
    const bf16* __restrict__ Vt_,
    const float* __restrict__ rn,
    const float* __restrict__ addm, const float* __restrict__ multm,
    float* __restrict__ Opart, float* __restrict__ Mb, float* __restrict__ Lb,
    int ch)
{
    __shared__ alignas(16) float mlds[4][2][2][16 * 32];  // [wave][buf][add|mult][row][col] = 32KB
    __shared__ alignas(16) bf16 plds[4][16 * 40];         // 5KB
    const int by = blockIdx.y;
    const int bh = by & (BH_ - 1), c = by >> 5;
    const int b = bh >> 3;
    const int kvb = c * ch;
    const int tid = threadIdx.x;
    const int w = tid >> 6, l = tid & 63, lr = l & 15, lg = l >> 4;
    const int q0 = blockIdx.x * 64 + w * 16;
    bf16* pl = &plds[w][0];

    const bf16* qb = &Qh_[((size_t)bh * N_ + q0 + lr) * D_];
    const bf16* qlb = &Ql_[((size_t)bh * N_ + q0 + lr) * D_];
    bf16x8 qh0 = *(const bf16x8*)(qb + lg * 8);
    bf16x8 qh1 = *(const bf16x8*)(qb + 32 + lg * 8);
    bf16x8 ql0 = *(const bf16x8*)(qlb + lg * 8);
    bf16x8 ql1 = *(const bf16x8*)(qlb + 32 + lg * 8);

    float rnr[4];
#pragma unroll
    for (int r = 0; r < 4; ++r) rnr[r] = rn[b * N_ + q0 + lg * 4 + r] * 0.125f;

    float mrun[4], lrun[4];
#pragma unroll
    for (int r = 0; r < 4; ++r) { mrun[r] = -3e38f; lrun[r] = 0.f; }
    f32x4 acc[4] = {};

    // staging source: lane covers row (l>>3), col (l&7)*4; one gload16 = 8 rows x 32 cols
    const size_t mb0 = (size_t)bh * N_ * N_;
    const float* astage = addm + mb0 + (size_t)(q0 + (l >> 3)) * N_ + (l & 7) * 4;
    const float* mstage = multm + mb0 + (size_t)(q0 + (l >> 3)) * N_ + (l & 7) * 4;

#define STAGE(kv, bi)                                          \
    do {                                                       \
        gload16(astage + (kv),           &mlds[w][bi][0][0]);  \
        gload16(astage + (kv) + 8 * N_,  &mlds[w][bi][0][256]);\
        gload16(mstage + (kv),           &mlds[w][bi][1][0]);  \
        gload16(mstage + (kv) + 8 * N_,  &mlds[w][bi][1][256]);\
    } while (0)

    STAGE(kvb, 0);

    const int nt = ch / KVB;
    for (int tile = 0; tile < nt; ++tile) {
        const int kv0 = kvb + tile * KVB;
        const int bi = tile & 1;

        // ---- K (8) + V (4) register loads, L2-resident ----
        bf16x8 kh[2][2], kl[2][2];
#pragma unroll
        for (int t = 0; t < 2; ++t) {
            const bf16* kb = &Kh_[((size_t)bh * N_ + kv0 + 16 * t + lr) * D_];
            const bf16* klb = &Kl_[((size_t)bh * N_ + kv0 + 16 * t + lr) * D_];
            kh[t][0] = *(const bf16x8*)(kb + lg * 8);
            kh[t][1] = *(const bf16x8*)(kb + 32 + lg * 8);
            kl[t][0] = *(const bf16x8*)(klb + lg * 8);
            kl[t][1] = *(const bf16x8*)(klb + 32 + lg * 8);
        }
        bf16x8 vv[4];
#pragma unroll
        for (int t = 0; t < 4; ++t)
            vv[t] = *(const bf16x8*)(&Vt_[((size_t)bh * D_ + 16 * t + lr) * N_ + kv0 + lg * 8]);
        __builtin_amdgcn_sched_barrier(0);

        // ---- prefetch next tile's masks into the other LDS buffer ----
        if (tile + 1 < nt) STAGE(kv0 + KVB, bi ^ 1);
        __builtin_amdgcn_sched_barrier(0);

        // K,V and current-tile masks complete; next-tile masks stay in flight
        if (tile + 1 < nt) { asm volatile("s_waitcnt vmcnt(4)" ::: "memory"); }
        else               { asm volatile("s_waitcnt vmcnt(0)" ::: "memory"); }
        __builtin_amdgcn_sched_barrier(0);

        // ---- S = Q K^T (hi/lo split, 6 MFMA per 16-col tile) ----
        f32x4 s[2];
#pragma unroll
        for (int t = 0; t < 2; ++t) {
            f32x4 z = {};
            z = MFMA16(qh0, kh[t][0], z, 0, 0, 0);
            z = MFMA16(qh1, kh[t][1], z, 0, 0, 0);
            z = MFMA16(ql0, kh[t][0], z, 0, 0, 0);
            z = MFMA16(ql1, kh[t][1], z, 0, 0, 0);
            z = MFMA16(qh0, kl[t][0], z, 0, 0, 0);
            z = MFMA16(qh1, kl[t][1], z, 0, 0, 0);
            s[t] = z;
        }

        // ---- masks from LDS, scale + add ----
        const float* at = &mlds[w][bi][0][0];
        const float* mt = &mlds[w][bi][1][0];
        float sv[2][4], mmul[2][4];
#pragma unroll
        for (int t = 0; t < 2; ++t) {
#pragma unroll
            for (int r = 0; r < 4; ++r) {
                int row = lg * 4 + r, col = 16 * t + lr;
                sv[t][r] = s[t][r] * rnr[r] + at[row * 32 + col];
                mmul[t][r] = mt[row * 32 + col];
            }
        }

        // ---- online softmax (row = 16-lane group) ----
        float pv[2][4];
#pragma unroll
        for (int r = 0; r < 4; ++r) {
            float v = fmaxf(sv[0][r], sv[1][r]);
            v = fmaxf(v, __shfl_xor(v, 1));
            v = fmaxf(v, __shfl_xor(v, 2));
            v = fmaxf(v, __shfl_xor(v, 4));
            v = fmaxf(v, __shfl_xor(v, 8));
            float mn = fmaxf(mrun[r], v);
            float rs = __expf(mrun[r] - mn);
            mrun[r] = mn;
            lrun[r] *= rs;
#pragma unroll
            for (int t = 0; t < 4; ++t) acc[t][r] *= rs;
            float rsum = 0.f;
#pragma unroll
            for (int t = 0; t < 2; ++t) { pv[t][r] = __expf(sv[t][r] - mn); rsum += pv[t][r]; }
            rsum += __shfl_xor(rsum, 1);
            rsum += __shfl_xor(rsum, 2);
            rsum += __shfl_xor(rsum, 4);
            rsum += __shfl_xor(rsum, 8);
            lrun[r] += rsum;
        }

        // ---- P_eff = exp * mult -> bf16 -> LDS (A-fragment layout fix) ----
#pragma unroll
        for (int t = 0; t < 2; ++t) {
#pragma unroll
            for (int r = 0; r < 4; ++r)
                pl[(lg * 4 + r) * 40 + 16 * t + lr] = (bf16)(pv[t][r] * mmul[t][r]);
        }

        // ---- O += P_eff @ V ----
        bf16x8 pa = *(const bf16x8*)(pl + lr * 40 + lg * 8);
#pragma unroll
        for (int t = 0; t < 4; ++t)
            acc[t] = MFMA16(pa, vv[t], acc[t], 0, 0, 0);
    }

    // ---- store unnormalized partials ----
    const size_t cb = ((size_t)c * BH_ + bh) * N_;
#pragma unroll
    for (int t = 0; t < 4; ++t) {
#pragma unroll
        for (int r = 0; r < 4; ++r) {
            int q = q0 + lg * 4 + r;
            Opart[(cb + q) * D_ + 16 * t + lr] = acc[t][r];
        }
    }
    if (lr == 0) {
#pragma unroll
        for (int r = 0; r < 4; ++r) {
            int q = q0 + lg * 4 + r;
            Mb[cb + q] = mrun[r];
            Lb[cb + q] = lrun[r];
        }
    }
#undef STAGE
}

// ---------- merge KV-split partials -> normalized attention out (hi/lo bf16) ----------
__global__ __launch_bounds__(256) void merge_kernel(
    const float* __restrict__ Opart, const float* __restrict__ Mb,
    const float* __restrict__ Lb,
    bf16* __restrict__ AOh, bf16* __restrict__ AOl, int ks)
{
    int idx = blockIdx.x * 256 + threadIdx.x;   // BH*N*(D/4)
    int bh = idx >> 14;
    int rem = idx & 16383;
    int q = rem >> 4, d4 = rem & 15;

    float M = -3e38f;
    for (int c = 0; c < ks; ++c)
        M = fmaxf(M, Mb[((size_t)c * BH_ + bh) * N_ + q]);
    float L = 0.f;
    f32x4 o = {};
    for (int c = 0; c < ks; ++c) {
        size_t base = ((size_t)c * BH_ + bh) * N_ + q;
        float wgt = __expf(Mb[base] - M);
        L += wgt * Lb[base];
        f32x4 v = *(const f32x4*)&Opart[base * D_ + d4 * 4];
        o += wgt * v;
    }
    float inv = 1.f / L;
    int b = bh >> 3, h = bh & 7;
    size_t ob = ((size_t)b * N_ + q) * E_ + h * D_ + d4 * 4;
    bf16x4 hi, lo;
#pragma unroll
    for (int j = 0; j < 4; ++j) {
        float x = o[j] * inv;
        bf16 hh = (bf16)x;
        hi[j] = hh;
        lo[j] = (bf16)(x - (float)hh);
    }
    *(bf16x4*)&AOh[ob] = hi;
    *(bf16x4*)&AOl[ob] = lo;
}

// ---------- output projection: split-bf16 (3-term), fp32 out + bias ----------
__global__ __launch_bounds__(256) void out_gemm(
    const bf16* __restrict__ Ah, const bf16* __restrict__ Al,
    const bf16* __restrict__ Wh, const bf16* __restrict__ Wl,
    const float* __restrict__ bias,
    float* __restrict__ out)
{
    const int e0 = blockIdx.x * 64;
    const int m0 = blockIdx.y * 64;
    const int tid = threadIdx.x;
    const int w = tid >> 6, l = tid & 63, lr = l & 15, lg = l >> 4;

    f32x4 acc[4] = {};
    const bf16* ah_p = &Ah[(size_t)(m0 + w * 16 + lr) * E_];
    const bf16* al_p = &Al[(size_t)(m0 + w * 16 + lr) * E_];

    for (int k0 = 0; k0 < E_; k0 += 32) {
        bf16x8 ah = *(const bf16x8*)(ah_p + k0 + lg * 8);
        bf16x8 al = *(const bf16x8*)(al_p + k0 + lg * 8);
#pragma unroll
        for (int t = 0; t < 4; ++t) {
            bf16x8 bh = *(const bf16x8*)(&Wh[(size_t)(e0 + 16 * t + lr) * E_ + k0 + lg * 8]);
            bf16x8 bl = *(const bf16x8*)(&Wl[(size_t)(e0 + 16 * t + lr) * E_ + k0 + lg * 8]);
            acc[t] = MFMA16(ah, bh, acc[t], 0, 0, 0);
            acc[t] = MFMA16(al, bh, acc[t], 0, 0, 0);
            acc[t] = MFMA16(ah, bl, acc[t], 0, 0, 0);
        }
    }

#pragma unroll
    for (int t = 0; t < 4; ++t) {
        float bv = bias[e0 + 16 * t + lr];
#pragma unroll
        for (int r = 0; r < 4; ++r) {
            int m = m0 + w * 16 + lg * 4 + r;
            out[(size_t)m * E_ + e0 + 16 * t + lr] = acc[t][r] + bv;
        }
    }
}

extern "C" void kernel_launch(void* const* d_in, const int* in_sizes, int n_in,
                              void* d_out, int out_size, void* d_ws, size_t ws_size,
                              hipStream_t stream) {
    const float* X = (const float*)d_in[0];
    const float* rn = (const float*)d_in[1];
    const float* addm = (const float*)d_in[2];
    const float* multm = (const float*)d_in[3];
    const float* Wq = (const float*)d_in[4];
    const float* bq = (const float*)d_in[5];
    const float* Wk = (const float*)d_in[6];
    const float* bk = (const float*)d_in[7];
    const float* Wv = (const float*)d_in[8];
    const float* bv = (const float*)d_in[9];
    const float* Wo = (const float*)d_in[10];
    const float* bo = (const float*)d_in[11];
    float* out = (float*)d_out;

    const size_t SZ_X = (size_t)B_ * N_ * E_;  // 2M elems
    const size_t SZ_W = (size_t)E_ * E_;       // 256K elems

    bf16* p = (bf16*)d_ws;
    bf16* Xh = p;  p += SZ_X;
    bf16* Xl = p;  p += SZ_X;
    bf16* Wqh = p; p += SZ_W;
    bf16* Wql = p; p += SZ_W;
    bf16* Wkh = p; p += SZ_W;
    bf16* Wkl = p; p += SZ_W;
    bf16* Wvh = p; p += SZ_W;
    bf16* Woh = p; p += SZ_W;
    bf16* Wol = p; p += SZ_W;
    bf16* Qh = p;  p += SZ_X;
    bf16* Ql = p;  p += SZ_X;
    bf16* Kh = p;  p += SZ_X;
    bf16* Kl = p;  p += SZ_X;
    bf16* Vt = p;  p += SZ_X;
    bf16* AOh = p; p += SZ_X;
    bf16* AOl = p; p += SZ_X;

    // KV-split factor chosen by workspace budget
    size_t fixed_bytes = (size_t)((char*)p - (char*)d_ws);
    size_t per_ks = (size_t)BH_ * N_ * D_ * 4 + (size_t)BH_ * N_ * 2 * 4;
    int ks = 4;
    if (fixed_bytes + 4 * per_ks > ws_size) ks = 2;
    if (fixed_bytes + 2 * per_ks > ws_size) ks = 1;

    float* Opart = (float*)p;
    float* Mb = Opart + (size_t)ks * BH_ * N_ * D_;
    float* Lb = Mb + (size_t)ks * BH_ * N_;

    const int NPREP = B_ * N_ * E_ + 4 * E_ * E_;
    prep_all<<<dim3(NPREP / 256), 256, 0, stream>>>(X, Wq, Wk, Wv, Wo,
        Xh, Xl, Wqh, Wql, Wkh, Wkl, Wvh, Woh, Wol);

    dim3 gq(E_ / 64, (B_ * N_) / 64, 3);  // (8, 64, 3)
    qkv_gemm<<<gq, 256, 0, stream>>>(Xh, Xl, Wqh, Wql, bq, Wkh, Wkl, bk, Wvh, bv,
                                     Qh, Ql, Kh, Kl, Vt);

    attn_kernel<<<dim3(N_ / 64, ks * BH_), 256, 0, stream>>>(
        Qh, Ql, Kh, Kl, Vt, rn, addm, multm, Opart, Mb, Lb, N_ / ks);

    merge_kernel<<<dim3((BH_ * N_ * (D_ / 4)) / 256), 256, 0, stream>>>(
        Opart, Mb, Lb, AOh, AOl, ks);

    dim3 gg(E_ / 64, (B_ * N_) / 64);
    out_gemm<<<gg, 256, 0, stream>>>(AOh, AOl, Woh, Wol, bo, out);
}

// Round 5
// 239.790 us; speedup vs baseline: 1.2876x; 1.1212x over previous
//
#include <hip/hip_runtime.h>

#define B_ 4
#define N_ 1024
#define E_ 512
#define H_ 8
#define D_ 64
#define BH_ 32
#define KVB 32

typedef __bf16 bf16;
typedef __bf16 bf16x8 __attribute__((ext_vector_type(8)));
typedef __bf16 bf16x4 __attribute__((ext_vector_type(4)));
typedef float f32x4 __attribute__((ext_vector_type(4)));

#define MFMA16 __builtin_amdgcn_mfma_f32_16x16x32_bf16

typedef const __attribute__((address_space(1))) void* gas_t;
typedef __attribute__((address_space(3))) void* las_t;

// global -> LDS direct, 16B/lane, 64 lanes = 1KB per call. LDS dest is
// wave-uniform base + lane*16 (linear); global src is per-lane (pre-swizzled).
__device__ __forceinline__ void gload16(const void* g, void* l) {
    __builtin_amdgcn_global_load_lds((gas_t)g, (las_t)l, 16, 0, 0);
}

// ---------- prep: all fp32 -> bf16 hi/lo conversions in one launch ----------
__global__ __launch_bounds__(256) void prep_all(
    const float* __restrict__ X, const float* __restrict__ Wq,
    const float* __restrict__ Wk, const float* __restrict__ Wv,
    const float* __restrict__ Wo,
    bf16* __restrict__ Xh, bf16* __restrict__ Xl,
    bf16* __restrict__ Wqh, bf16* __restrict__ Wql,
    bf16* __restrict__ Wkh, bf16* __restrict__ Wkl,
    bf16* __restrict__ Wvh,
    bf16* __restrict__ Woh, bf16* __restrict__ Wol)
{
    const int NX = B_ * N_ * E_;   // 2M
    const int NW = E_ * E_;        // 256K
    int i = blockIdx.x * 256 + threadIdx.x;
    if (i < NX) {
        float x = X[i]; bf16 h = (bf16)x;
        Xh[i] = h; Xl[i] = (bf16)(x - (float)h);
        return;
    }
    i -= NX;
    int w = i >> 18, j = i & (NW - 1);
    if (w == 0) { float x = Wq[j]; bf16 h = (bf16)x; Wqh[j] = h; Wql[j] = (bf16)(x - (float)h); }
    else if (w == 1) { float x = Wk[j]; bf16 h = (bf16)x; Wkh[j] = h; Wkl[j] = (bf16)(x - (float)h); }
    else if (w == 2) { float x = Wv[j]; Wvh[j] = (bf16)x; }
    else if (w == 3) { float x = Wo[j]; bf16 h = (bf16)x; Woh[j] = h; Wol[j] = (bf16)(x - (float)h); }
}

// ---------- fused QKV projection: z=0 -> Q (hi/lo), z=1 -> K (hi/lo), z=2 -> V^T ----------
__global__ __launch_bounds__(256) void qkv_gemm(
    const bf16* __restrict__ Xh, const bf16* __restrict__ Xl,
    const bf16* __restrict__ Wqh, const bf16* __restrict__ Wql, const float* __restrict__ bq,
    const bf16* __restrict__ Wkh, const bf16* __restrict__ Wkl, const float* __restrict__ bk,
    const bf16* __restrict__ Wvh, const float* __restrict__ bvv,
    bf16* __restrict__ Qh, bf16* __restrict__ Ql,
    bf16* __restrict__ Kh, bf16* __restrict__ Kl,
    bf16* __restrict__ Vt)
{
    __shared__ alignas(16) bf16 lds[64 * 72];
    const int z = blockIdx.z;
    const int e0 = blockIdx.x * 64;
    const int m0 = blockIdx.y * 64;
    const int tid = threadIdx.x;
    const int w = tid >> 6, l = tid & 63, lr = l & 15, lg = l >> 4;
    const int h = e0 >> 6;

    const bf16* xh = &Xh[(size_t)(m0 + w * 16 + lr) * E_];

    if (z == 2) {
        f32x4 acc[4] = {};
        for (int k0 = 0; k0 < E_; k0 += 32) {
            bf16x8 ah = *(const bf16x8*)(xh + k0 + lg * 8);
#pragma unroll
            for (int t = 0; t < 4; ++t) {
                bf16x8 bh = *(const bf16x8*)(&Wvh[(size_t)(e0 + 16 * t + lr) * E_ + k0 + lg * 8]);
                acc[t] = MFMA16(ah, bh, acc[t], 0, 0, 0);
            }
        }
#pragma unroll
        for (int t = 0; t < 4; ++t) {
            float bv = bvv[e0 + 16 * t + lr];
#pragma unroll
            for (int r = 0; r < 4; ++r)
                lds[(16 * t + lr) * 72 + w * 16 + lg * 4 + r] = (bf16)(acc[t][r] + bv);
        }
        __syncthreads();
        int d = tid >> 2, c0 = (tid & 3) * 16;
        int b = m0 >> 10, n = (m0 & (N_ - 1)) + c0;
        bf16x8* dst = (bf16x8*)&Vt[((size_t)(b * H_ + h) * D_ + d) * N_ + n];
        const bf16x8* s = (const bf16x8*)&lds[d * 72 + c0];
        dst[0] = s[0];
        dst[1] = s[1];
        return;
    }

    const bf16* Wh = z ? Wkh : Wqh;
    const bf16* Wl = z ? Wkl : Wql;
    const float* bias = z ? bk : bq;
    bf16* Oh = z ? Kh : Qh;
    bf16* Ol = z ? Kl : Ql;

    f32x4 acc[4] = {};
    const bf16* xl = &Xl[(size_t)(m0 + w * 16 + lr) * E_];
    for (int k0 = 0; k0 < E_; k0 += 32) {
        bf16x8 ah = *(const bf16x8*)(xh + k0 + lg * 8);
        bf16x8 al = *(const bf16x8*)(xl + k0 + lg * 8);
#pragma unroll
        for (int t = 0; t < 4; ++t) {
            bf16x8 bh = *(const bf16x8*)(&Wh[(size_t)(e0 + 16 * t + lr) * E_ + k0 + lg * 8]);
            bf16x8 bl = *(const bf16x8*)(&Wl[(size_t)(e0 + 16 * t + lr) * E_ + k0 + lg * 8]);
            acc[t] = MFMA16(ah, bh, acc[t], 0, 0, 0);
            acc[t] = MFMA16(al, bh, acc[t], 0, 0, 0);
            acc[t] = MFMA16(ah, bl, acc[t], 0, 0, 0);
        }
    }
#pragma unroll
    for (int t = 0; t < 4; ++t) {
        float bv = bias[e0 + 16 * t + lr];
#pragma unroll
        for (int r = 0; r < 4; ++r) {
            int m = m0 + w * 16 + lg * 4 + r;
            int b = m >> 10, n = m & (N_ - 1);
            float v = acc[t][r] + bv;
            bf16 hi = (bf16)v;
            size_t idx = ((size_t)(b * H_ + h) * N_ + n) * D_ + 16 * t + lr;
            Oh[idx] = hi;
            Ol[idx] = (bf16)(v - (float)hi);
        }
    }
}

// ---------- fused attention: ALL bulk loads via global_load_lds (zero VGPR) ----------
// grid (N_/64, ks*BH_), 256 thr. KV tile = 32. K/V block-shared in LDS; masks
// per-wave in LDS. Double-buffered; counted vmcnt(7); raw s_barrier protocol.
// XOR-swizzled LDS (pre-swizzled global source, swizzled LDS reads).
__global__ __launch_bounds__(256) void attn_kernel(
    const bf16* __restrict__ Qh_, const bf16* __restrict__ Ql_,
    const bf16* __restrict__ Kh_, const bf16* __restrict__ Kl_,
    const bf16* __restrict__ Vt_,
    const float* __restrict__ rn,
    const float* __restrict__ addm, const float* __restrict__ multm,
    float* __restrict__ Opart, float* __restrict__ Mb, float* __restrict__ Lb,
    int ch)
{
    __shared__ alignas(16) float mlds[4][2][2][16 * 32];   // 32 KB masks (per-wave)
    __shared__ alignas(16) bf16 khlds[2][32 * 64];         // 8 KB
    __shared__ alignas(16) bf16 kllds[2][32 * 64];         // 8 KB
    __shared__ alignas(16) bf16 vlds[2][64 * 32];          // 8 KB
    __shared__ alignas(16) bf16 plds[4][16 * 40];          // 5 KB

    const int by = blockIdx.y;
    const int bh = by & (BH_ - 1), c = by >> 5;
    const int b = bh >> 3;
    const int kvb = c * ch;
    const int tid = threadIdx.x;
    const int w = tid >> 6, l = tid & 63, lr = l & 15, lg = l >> 4;
    const int q0 = blockIdx.x * 64 + w * 16;
    bf16* pl = &plds[w][0];

    // ---- Q fragments (hi/lo) in registers ----
    const bf16* qb = &Qh_[((size_t)bh * N_ + q0 + lr) * D_];
    const bf16* qlb = &Ql_[((size_t)bh * N_ + q0 + lr) * D_];
    bf16x8 qh0 = *(const bf16x8*)(qb + lg * 8);
    bf16x8 qh1 = *(const bf16x8*)(qb + 32 + lg * 8);
    bf16x8 ql0 = *(const bf16x8*)(qlb + lg * 8);
    bf16x8 ql1 = *(const bf16x8*)(qlb + 32 + lg * 8);

    float rnr[4];
#pragma unroll
    for (int r = 0; r < 4; ++r) rnr[r] = rn[b * N_ + q0 + lg * 4 + r] * 0.125f;

    float mrun[4], lrun[4];
#pragma unroll
    for (int r = 0; r < 4; ++r) { mrun[r] = -3e38f; lrun[r] = 0.f; }
    f32x4 acc[4] = {};

    // ---- pre-swizzled global source addresses ----
    // masks: 16 rows x 128B; row = (l>>3), col_f32 = 4*((l&7)^((l>>3)&7))
    const size_t mb0 = (size_t)bh * N_ * N_;
    const int mrow = l >> 3, mcol = 4 * ((l & 7) ^ ((l >> 3) & 7));
    const float* asrc = addm + mb0 + (size_t)(q0 + mrow) * N_ + mcol;
    const float* msrc = multm + mb0 + (size_t)(q0 + mrow) * N_ + mcol;
    // K: 32 rows x 128B; this wave stages rows 8w..8w+7
    const int krow = 8 * w + (l >> 3), kcol = 8 * ((l & 7) ^ ((l >> 3) & 7));
    const bf16* khsrc = Kh_ + ((size_t)bh * N_ + krow) * D_ + kcol;
    const bf16* klsrc = Kl_ + ((size_t)bh * N_ + krow) * D_ + kcol;
    // V: 64 rows(d) x 64B; this wave stages d = 16w..16w+15
    const int vrow = 16 * w + (l >> 2), vcol = 8 * ((l & 3) ^ ((l >> 2) & 3));
    const bf16* vsrc = Vt_ + ((size_t)bh * D_ + vrow) * N_ + vcol;

#define STAGE(kv, bi)                                                     \
    do {                                                                  \
        gload16(asrc + (kv), &mlds[w][bi][0][0]);                         \
        gload16(asrc + (kv) + 8 * N_, &mlds[w][bi][0][256]);              \
        gload16(msrc + (kv), &mlds[w][bi][1][0]);                         \
        gload16(msrc + (kv) + 8 * N_, &mlds[w][bi][1][256]);              \
        gload16(khsrc + (size_t)(kv) * D_, &khlds[bi][w * 512]);          \
        gload16(klsrc + (size_t)(kv) * D_, &kllds[bi][w * 512]);          \
        gload16(vsrc + (kv), &vlds[bi][w * 512]);                         \
    } while (0)

    STAGE(kvb, 0);

    const int nt = ch / KVB;
    for (int tile = 0; tile < nt; ++tile) {
        const int kv0 = kvb + tile * KVB;
        const int bi = tile & 1;

        if (tile + 1 < nt) {
            STAGE(kv0 + KVB, bi ^ 1);
            __builtin_amdgcn_sched_barrier(0);
            asm volatile("s_waitcnt vmcnt(7)" ::: "memory");
        } else {
            asm volatile("s_waitcnt vmcnt(0)" ::: "memory");
        }
        __builtin_amdgcn_sched_barrier(0);
        __builtin_amdgcn_s_barrier();   // all waves' stage(t) complete

        // ---- K fragments from LDS (swizzled reads) ----
        const char* khb = (const char*)&khlds[bi][0];
        const char* klb = (const char*)&kllds[bi][0];
        const int ksw = (lr & 7) << 4;
        bf16x8 kh[2][2], kl[2][2];
#pragma unroll
        for (int t = 0; t < 2; ++t) {
            int rb = (16 * t + lr) * 128;
            kh[t][0] = *(const bf16x8*)(khb + rb + ((lg * 16) ^ ksw));
            kh[t][1] = *(const bf16x8*)(khb + rb + ((64 + lg * 16) ^ ksw));
            kl[t][0] = *(const bf16x8*)(klb + rb + ((lg * 16) ^ ksw));
            kl[t][1] = *(const bf16x8*)(klb + rb + ((64 + lg * 16) ^ ksw));
        }

        // ---- S = Q K^T (hi/lo split) ----
        f32x4 s[2];
#pragma unroll
        for (int t = 0; t < 2; ++t) {
            f32x4 z = {};
            z = MFMA16(qh0, kh[t][0], z, 0, 0, 0);
            z = MFMA16(qh1, kh[t][1], z, 0, 0, 0);
            z = MFMA16(ql0, kh[t][0], z, 0, 0, 0);
            z = MFMA16(ql1, kh[t][1], z, 0, 0, 0);
            z = MFMA16(qh0, kl[t][0], z, 0, 0, 0);
            z = MFMA16(qh1, kl[t][1], z, 0, 0, 0);
            s[t] = z;
        }

        // ---- masks from LDS (swizzled), scale + add ----
        const float* at = &mlds[w][bi][0][0];
        const float* mt = &mlds[w][bi][1][0];
        float sv[2][4], mmul[2][4];
#pragma unroll
        for (int t = 0; t < 2; ++t) {
#pragma unroll
            for (int r = 0; r < 4; ++r) {
                int row = lg * 4 + r;
                int swf = (row & 7) << 2;
                int col = (16 * t + lr) ^ swf;
                sv[t][r] = s[t][r] * rnr[r] + at[row * 32 + col];
                mmul[t][r] = mt[row * 32 + col];
            }
        }

        // ---- online softmax (row = 16-lane group) ----
        float pv[2][4];
#pragma unroll
        for (int r = 0; r < 4; ++r) {
            float v = fmaxf(sv[0][r], sv[1][r]);
            v = fmaxf(v, __shfl_xor(v, 1));
            v = fmaxf(v, __shfl_xor(v, 2));
            v = fmaxf(v, __shfl_xor(v, 4));
            v = fmaxf(v, __shfl_xor(v, 8));
            float mn = fmaxf(mrun[r], v);
            float rs = __expf(mrun[r] - mn);
            mrun[r] = mn;
            lrun[r] *= rs;
#pragma unroll
            for (int t = 0; t < 4; ++t) acc[t][r] *= rs;
            float rsum = 0.f;
#pragma unroll
            for (int t = 0; t < 2; ++t) { pv[t][r] = __expf(sv[t][r] - mn); rsum += pv[t][r]; }
            rsum += __shfl_xor(rsum, 1);
            rsum += __shfl_xor(rsum, 2);
            rsum += __shfl_xor(rsum, 4);
            rsum += __shfl_xor(rsum, 8);
            lrun[r] += rsum;
        }

        // ---- P_eff = exp * mult -> bf16 -> per-wave LDS (A-frag layout fix) ----
#pragma unroll
        for (int t = 0; t < 2; ++t) {
#pragma unroll
            for (int r = 0; r < 4; ++r)
                pl[(lg * 4 + r) * 40 + 16 * t + lr] = (bf16)(pv[t][r] * mmul[t][r]);
        }

        // ---- O += P_eff @ V (V from LDS, swizzled) ----
        bf16x8 pa = *(const bf16x8*)(pl + lr * 40 + lg * 8);
        const char* vb = (const char*)&vlds[bi][0];
#pragma unroll
        for (int t = 0; t < 4; ++t) {
            int row = 16 * t + lr;
            bf16x8 vfrag = *(const bf16x8*)(vb + row * 64 + ((lg * 16) ^ ((lr & 3) << 4)));
            acc[t] = MFMA16(pa, vfrag, acc[t], 0, 0, 0);
        }

        __builtin_amdgcn_s_barrier();   // all waves done reading buf[t]
    }

    // ---- store unnormalized partials ----
    const size_t cb = ((size_t)c * BH_ + bh) * N_;
#pragma unroll
    for (int t = 0; t < 4; ++t) {
#pragma unroll
        for (int r = 0; r < 4; ++r) {
            int q = q0 + lg * 4 + r;
            Opart[(cb + q) * D_ + 16 * t + lr] = acc[t][r];
        }
    }
    if (lr == 0) {
#pragma unroll
        for (int r = 0; r < 4; ++r) {
            int q = q0 + lg * 4 + r;
            Mb[cb + q] = mrun[r];
            Lb[cb + q] = lrun[r];
        }
    }
#undef STAGE
}

// ---------- merge KV-split partials -> normalized attention out (hi/lo bf16) ----------
__global__ __launch_bounds__(256) void merge_kernel(
    const float* __restrict__ Opart, const float* __restrict__ Mb,
    const float* __restrict__ Lb,
    bf16* __restrict__ AOh, bf16* __restrict__ AOl, int ks)
{
    int idx = blockIdx.x * 256 + threadIdx.x;   // BH*N*(D/4)
    int bh = idx >> 14;
    int rem = idx & 16383;
    int q = rem >> 4, d4 = rem & 15;

    float M = -3e38f;
    for (int c = 0; c < ks; ++c)
        M = fmaxf(M, Mb[((size_t)c * BH_ + bh) * N_ + q]);
    float L = 0.f;
    f32x4 o = {};
    for (int c = 0; c < ks; ++c) {
        size_t base = ((size_t)c * BH_ + bh) * N_ + q;
        float wgt = __expf(Mb[base] - M);
        L += wgt * Lb[base];
        f32x4 v = *(const f32x4*)&Opart[base * D_ + d4 * 4];
        o += wgt * v;
    }
    float inv = 1.f / L;
    int b = bh >> 3, h = bh & 7;
    size_t ob = ((size_t)b * N_ + q) * E_ + h * D_ + d4 * 4;
    bf16x4 hi, lo;
#pragma unroll
    for (int j = 0; j < 4; ++j) {
        float x = o[j] * inv;
        bf16 hh = (bf16)x;
        hi[j] = hh;
        lo[j] = (bf16)(x - (float)hh);
    }
    *(bf16x4*)&AOh[ob] = hi;
    *(bf16x4*)&AOl[ob] = lo;
}

// ---------- output projection: split-bf16 (3-term), fp32 out + bias ----------
__global__ __launch_bounds__(256) void out_gemm(
    const bf16* __restrict__ Ah, const bf16* __restrict__ Al,
    const bf16* __restrict__ Wh, const bf16* __restrict__ Wl,
    const float* __restrict__ bias,
    float* __restrict__ out)
{
    const int e0 = blockIdx.x * 64;
    const int m0 = blockIdx.y * 64;
    const int tid = threadIdx.x;
    const int w = tid >> 6, l = tid & 63, lr = l & 15, lg = l >> 4;

    f32x4 acc[4] = {};
    const bf16* ah_p = &Ah[(size_t)(m0 + w * 16 + lr) * E_];
    const bf16* al_p = &Al[(size_t)(m0 + w * 16 + lr) * E_];

    for (int k0 = 0; k0 < E_; k0 += 32) {
        bf16x8 ah = *(const bf16x8*)(ah_p + k0 + lg * 8);
        bf16x8 al = *(const bf16x8*)(al_p + k0 + lg * 8);
#pragma unroll
        for (int t = 0; t < 4; ++t) {
            bf16x8 bh = *(const bf16x8*)(&Wh[(size_t)(e0 + 16 * t + lr) * E_ + k0 + lg * 8]);
            bf16x8 bl = *(const bf16x8*)(&Wl[(size_t)(e0 + 16 * t + lr) * E_ + k0 + lg * 8]);
            acc[t] = MFMA16(ah, bh, acc[t], 0, 0, 0);
            acc[t] = MFMA16(al, bh, acc[t], 0, 0, 0);
            acc[t] = MFMA16(ah, bl, acc[t], 0, 0, 0);
        }
    }

#pragma unroll
    for (int t = 0; t < 4; ++t) {
        float bv = bias[e0 + 16 * t + lr];
#pragma unroll
        for (int r = 0; r < 4; ++r) {
            int m = m0 + w * 16 + lg * 4 + r;
            out[(size_t)m * E_ + e0 + 16 * t + lr] = acc[t][r] + bv;
        }
    }
}

extern "C" void kernel_launch(void* const* d_in, const int* in_sizes, int n_in,
                              void* d_out, int out_size, void* d_ws, size_t ws_size,
                              hipStream_t stream) {
    const float* X = (const float*)d_in[0];
    const float* rn = (const float*)d_in[1];
    const float* addm = (const float*)d_in[2];
    const float* multm = (const float*)d_in[3];
    const float* Wq = (const float*)d_in[4];
    const float* bq = (const float*)d_in[5];
    const float* Wk = (const float*)d_in[6];
    const float* bk = (const float*)d_in[7];
    const float* Wv = (const float*)d_in[8];
    const float* bv = (const float*)d_in[9];
    const float* Wo = (const float*)d_in[10];
    const float* bo = (const float*)d_in[11];
    float* out = (float*)d_out;

    const size_t SZ_X = (size_t)B_ * N_ * E_;  // 2M elems
    const size_t SZ_W = (size_t)E_ * E_;       // 256K elems

    bf16* p = (bf16*)d_ws;
    bf16* Xh = p;  p += SZ_X;
    bf16* Xl = p;  p += SZ_X;
    bf16* Wqh = p; p += SZ_W;
    bf16* Wql = p; p += SZ_W;
    bf16* Wkh = p; p += SZ_W;
    bf16* Wkl = p; p += SZ_W;
    bf16* Wvh = p; p += SZ_W;
    bf16* Woh = p; p += SZ_W;
    bf16* Wol = p; p += SZ_W;
    bf16* Qh = p;  p += SZ_X;
    bf16* Ql = p;  p += SZ_X;
    bf16* Kh = p;  p += SZ_X;
    bf16* Kl = p;  p += SZ_X;
    bf16* Vt = p;  p += SZ_X;
    bf16* AOh = p; p += SZ_X;
    bf16* AOl = p; p += SZ_X;

    // KV-split factor chosen by workspace budget
    size_t fixed_bytes = (size_t)((char*)p - (char*)d_ws);
    size_t per_ks = (size_t)BH_ * N_ * D_ * 4 + (size_t)BH_ * N_ * 2 * 4;
    int ks = 4;
    if (fixed_bytes + 4 * per_ks > ws_size) ks = 2;
    if (fixed_bytes + 2 * per_ks > ws_size) ks = 1;

    float* Opart = (float*)p;
    float* Mb = Opart + (size_t)ks * BH_ * N_ * D_;
    float* Lb = Mb + (size_t)ks * BH_ * N_;

    const int NPREP = B_ * N_ * E_ + 4 * E_ * E_;
    prep_all<<<dim3(NPREP / 256), 256, 0, stream>>>(X, Wq, Wk, Wv, Wo,
        Xh, Xl, Wqh, Wql, Wkh, Wkl, Wvh, Woh, Wol);

    dim3 gq(E_ / 64, (B_ * N_) / 64, 3);
    qkv_gemm<<<gq, 256, 0, stream>>>(Xh, Xl, Wqh, Wql, bq, Wkh, Wkl, bk, Wvh, bv,
                                     Qh, Ql, Kh, Kl, Vt);

    attn_kernel<<<dim3(N_ / 64, ks * BH_), 256, 0, stream>>>(
        Qh, Ql, Kh, Kl, Vt, rn, addm, multm, Opart, Mb, Lb, N_ / ks);

    merge_kernel<<<dim3((BH_ * N_ * (D_ / 4)) / 256), 256, 0, stream>>>(
        Opart, Mb, Lb, AOh, AOl, ks);

    dim3 gg(E_ / 64, (B_ * N_) / 64);
    out_gemm<<<gg, 256, 0, stream>>>(AOh, AOl, Woh, Wol, bo, out);
}

// Round 6
// 157.444 us; speedup vs baseline: 1.9610x; 1.5230x over previous
//
#include <hip/hip_runtime.h>

#define B_ 4
#define N_ 1024
#define E_ 512
#define H_ 8
#define D_ 64
#define BH_ 32
#define KVB 32

typedef __bf16 bf16;
typedef __bf16 bf16x8 __attribute__((ext_vector_type(8)));
typedef __bf16 bf16x4 __attribute__((ext_vector_type(4)));
typedef float f32x4 __attribute__((ext_vector_type(4)));

#define MFMA16 __builtin_amdgcn_mfma_f32_16x16x32_bf16

typedef const __attribute__((address_space(1))) void* gas_t;
typedef __attribute__((address_space(3))) void* las_t;

__device__ __forceinline__ void gload16(const void* g, void* l) {
    __builtin_amdgcn_global_load_lds((gas_t)g, (las_t)l, 16, 0, 0);
}

// ---------- prep: all fp32 -> bf16 hi/lo conversions in one launch ----------
__global__ __launch_bounds__(256) void prep_all(
    const float* __restrict__ X, const float* __restrict__ Wq,
    const float* __restrict__ Wk, const float* __restrict__ Wv,
    const float* __restrict__ Wo,
    bf16* __restrict__ Xh, bf16* __restrict__ Xl,
    bf16* __restrict__ Wqh, bf16* __restrict__ Wql,
    bf16* __restrict__ Wkh, bf16* __restrict__ Wkl,
    bf16* __restrict__ Wvh,
    bf16* __restrict__ Woh, bf16* __restrict__ Wol)
{
    const int NX = B_ * N_ * E_;
    const int NW = E_ * E_;
    int i = blockIdx.x * 256 + threadIdx.x;
    if (i < NX) {
        float x = X[i]; bf16 h = (bf16)x;
        Xh[i] = h; Xl[i] = (bf16)(x - (float)h);
        return;
    }
    i -= NX;
    int w = i >> 18, j = i & (NW - 1);
    if (w == 0) { float x = Wq[j]; bf16 h = (bf16)x; Wqh[j] = h; Wql[j] = (bf16)(x - (float)h); }
    else if (w == 1) { float x = Wk[j]; bf16 h = (bf16)x; Wkh[j] = h; Wkl[j] = (bf16)(x - (float)h); }
    else if (w == 2) { float x = Wv[j]; Wvh[j] = (bf16)x; }
    else if (w == 3) { float x = Wo[j]; bf16 h = (bf16)x; Woh[j] = h; Wol[j] = (bf16)(x - (float)h); }
}

// ---------- fused QKV projection with W-tile LDS staging ----------
// z=0 -> Q (hi/lo out), z=1 -> K (hi/lo out), z=2 -> V^T
__global__ __launch_bounds__(256) void qkv_gemm(
    const bf16* __restrict__ Xh, const bf16* __restrict__ Xl,
    const bf16* __restrict__ Wqh, const bf16* __restrict__ Wql, const float* __restrict__ bq,
    const bf16* __restrict__ Wkh, const bf16* __restrict__ Wkl, const float* __restrict__ bk,
    const bf16* __restrict__ Wvh, const float* __restrict__ bvv,
    bf16* __restrict__ Qh, bf16* __restrict__ Ql,
    bf16* __restrict__ Kh, bf16* __restrict__ Kl,
    bf16* __restrict__ Vt)
{
    __shared__ alignas(16) bf16 wlds[2][2][64 * 32];   // [buf][hi/lo][64 rows][32 k] = 16 KB
    __shared__ alignas(16) bf16 tlds[64 * 72];         // V-transpose buffer
    const int z = blockIdx.z;
    const int e0 = blockIdx.x * 64;
    const int m0 = blockIdx.y * 64;
    const int tid = threadIdx.x;
    const int w = tid >> 6, l = tid & 63, lr = l & 15, lg = l >> 4;
    const int h = e0 >> 6;
    const bool three = (z != 2);

    const bf16* Wh = (z == 0) ? Wqh : ((z == 1) ? Wkh : Wvh);
    const bf16* Wl = (z == 0) ? Wql : ((z == 1) ? Wkl : Wqh /*unused*/);

    // staging: wave w covers rows 16w..16w+15; pre-swizzled source col
    const int wrow = 16 * w + (l >> 2);
    const int wcol = 8 * ((l & 3) ^ ((l >> 3) & 3));
    const bf16* whsrc = Wh + (size_t)(e0 + wrow) * E_ + wcol;
    const bf16* wlsrc = Wl + (size_t)(e0 + wrow) * E_ + wcol;

#define WSTAGE(k0, bi) do {                                  \
        gload16(whsrc + (k0), &wlds[bi][0][w * 512]);        \
        if (three) gload16(wlsrc + (k0), &wlds[bi][1][w * 512]); \
    } while (0)

    WSTAGE(0, 0);

    f32x4 acc[4] = {};
    const bf16* xh = &Xh[(size_t)(m0 + w * 16 + lr) * E_];
    const bf16* xl = &Xl[(size_t)(m0 + w * 16 + lr) * E_];

    for (int it = 0; it < 16; ++it) {
        const int k0 = it * 32;
        const int bi = it & 1;
        if (it < 15) {
            WSTAGE(k0 + 32, bi ^ 1);
            __builtin_amdgcn_sched_barrier(0);
            if (three) asm volatile("s_waitcnt vmcnt(2)" ::: "memory");
            else       asm volatile("s_waitcnt vmcnt(1)" ::: "memory");
        } else {
            asm volatile("s_waitcnt vmcnt(0)" ::: "memory");
        }
        __builtin_amdgcn_sched_barrier(0);
        __builtin_amdgcn_s_barrier();

        bf16x8 ah = *(const bf16x8*)(xh + k0 + lg * 8);
        bf16x8 al = three ? *(const bf16x8*)(xl + k0 + lg * 8) : ah;

        const char* whb = (const char*)&wlds[bi][0][0];
        const char* wlb = (const char*)&wlds[bi][1][0];
        const int wsw = ((lr >> 1) & 3) << 4;
#pragma unroll
        for (int t = 0; t < 4; ++t) {
            int rb = (16 * t + lr) * 64;
            bf16x8 bh = *(const bf16x8*)(whb + rb + ((lg * 16) ^ wsw));
            acc[t] = MFMA16(ah, bh, acc[t], 0, 0, 0);
            if (three) {
                bf16x8 bl = *(const bf16x8*)(wlb + rb + ((lg * 16) ^ wsw));
                acc[t] = MFMA16(al, bh, acc[t], 0, 0, 0);
                acc[t] = MFMA16(ah, bl, acc[t], 0, 0, 0);
            }
        }
        __builtin_amdgcn_s_barrier();
    }
#undef WSTAGE

    if (z == 2) {
        // V path epilogue: transpose via LDS -> Vt [B*H][D][N]
        const float* bias = bvv;
#pragma unroll
        for (int t = 0; t < 4; ++t) {
            float bv = bias[e0 + 16 * t + lr];
#pragma unroll
            for (int r = 0; r < 4; ++r)
                tlds[(16 * t + lr) * 72 + w * 16 + lg * 4 + r] = (bf16)(acc[t][r] + bv);
        }
        __syncthreads();
        int d = tid >> 2, c0 = (tid & 3) * 16;
        int b = m0 >> 10, n = (m0 & (N_ - 1)) + c0;
        bf16x8* dst = (bf16x8*)&Vt[((size_t)(b * H_ + h) * D_ + d) * N_ + n];
        const bf16x8* s = (const bf16x8*)&tlds[d * 72 + c0];
        dst[0] = s[0];
        dst[1] = s[1];
        return;
    }

    const float* bias = z ? bk : bq;
    bf16* Oh = z ? Kh : Qh;
    bf16* Ol = z ? Kl : Ql;
#pragma unroll
    for (int t = 0; t < 4; ++t) {
        float bv = bias[e0 + 16 * t + lr];
#pragma unroll
        for (int r = 0; r < 4; ++r) {
            int m = m0 + w * 16 + lg * 4 + r;
            int b = m >> 10, n = m & (N_ - 1);
            float v = acc[t][r] + bv;
            bf16 hi = (bf16)v;
            size_t idx = ((size_t)(b * H_ + h) * N_ + n) * D_ + 16 * t + lr;
            Oh[idx] = hi;
            Ol[idx] = (bf16)(v - (float)hi);
        }
    }
}

// ---------- fused attention: SWAPPED QK^T (S^T layout) ----------
// grid (N_/64, ks*BH_), 256 thr. Masks+K staged via global_load_lds (dbuf,
// XOR-swizzled, counted vmcnt); V direct from L2; per-lane softmax state.
__global__ __launch_bounds__(256) void attn_kernel(
    const bf16* __restrict__ Qh_, const bf16* __restrict__ Ql_,
    const bf16* __restrict__ Kh_, const bf16* __restrict__ Kl_,
    const bf16* __restrict__ Vt_,
    const float* __restrict__ rn,
    const float* __restrict__ addm, const float* __restrict__ multm,
    float* __restrict__ Opart, float* __restrict__ Mb, float* __restrict__ Lb,
    int ch)
{
    __shared__ alignas(16) float mlds[4][2][2][16 * 32];   // 32 KB per-wave mask bufs
    __shared__ alignas(16) bf16 khlds[2][32 * 64];         // 8 KB
    __shared__ alignas(16) bf16 kllds[2][32 * 64];         // 8 KB
    __shared__ alignas(16) bf16 plds[4][16 * 40];          // 5 KB   total 53 KB -> 3 blk/CU

    const int by = blockIdx.y;
    const int bh = by & (BH_ - 1), c = by >> 5;
    const int b = bh >> 3;
    const int kvb = c * ch;
    const int tid = threadIdx.x;
    const int w = tid >> 6, l = tid & 63, lr = l & 15, lg = l >> 4;
    const int q0 = blockIdx.x * 64 + w * 16;
    bf16* pw = &plds[w][0];

    // Q fragments (B-operand): lane holds Q[q0+lr][8lg..] and [32+8lg..]
    const bf16* qb = &Qh_[((size_t)bh * N_ + q0 + lr) * D_];
    const bf16* qlb = &Ql_[((size_t)bh * N_ + q0 + lr) * D_];
    bf16x8 qh0 = *(const bf16x8*)(qb + lg * 8);
    bf16x8 qh1 = *(const bf16x8*)(qb + 32 + lg * 8);
    bf16x8 ql0 = *(const bf16x8*)(qlb + lg * 8);
    bf16x8 ql1 = *(const bf16x8*)(qlb + 32 + lg * 8);

    const float rnq = rn[b * N_ + q0 + lr] * 0.125f;   // one scalar per lane (q = lr)

    float mrun = -3e38f, lrun = 0.f;                   // per-lane (replicated over lg)
    f32x4 acc[4] = {};                                 // acc[t'][r] = O^T[16t'+4lg+r][q0+lr]

    // pre-swizzled staging sources
    const size_t mb0 = (size_t)bh * N_ * N_;
    const int mrow = l >> 3, mcol = 4 * ((l & 7) ^ ((l >> 3) & 7));
    const float* asrc = addm + mb0 + (size_t)(q0 + mrow) * N_ + mcol;
    const float* msrc = multm + mb0 + (size_t)(q0 + mrow) * N_ + mcol;
    const int krow = 8 * w + (l >> 3), kcol = 8 * ((l & 7) ^ ((l >> 3) & 7));
    const bf16* khsrc = Kh_ + ((size_t)bh * N_ + krow) * D_ + kcol;
    const bf16* klsrc = Kl_ + ((size_t)bh * N_ + krow) * D_ + kcol;
    // V direct-load base: row (bh*64 + 16t' + lr), col kv0 + 8lg
    const bf16* vbase = Vt_ + ((size_t)bh * D_ + lr) * N_ + 8 * lg;

#define STAGE(kv, bi)                                                     \
    do {                                                                  \
        gload16(asrc + (kv), &mlds[w][bi][0][0]);                         \
        gload16(asrc + (kv) + 8 * N_, &mlds[w][bi][0][256]);              \
        gload16(msrc + (kv), &mlds[w][bi][1][0]);                         \
        gload16(msrc + (kv) + 8 * N_, &mlds[w][bi][1][256]);              \
        gload16(khsrc + (size_t)(kv) * D_, &khlds[bi][w * 512]);          \
        gload16(klsrc + (size_t)(kv) * D_, &kllds[bi][w * 512]);          \
    } while (0)

    STAGE(kvb, 0);

    const int nt = ch / KVB;
    for (int tile = 0; tile < nt; ++tile) {
        const int kv0 = kvb + tile * KVB;
        const int bi = tile & 1;

        if (tile + 1 < nt) {
            STAGE(kv0 + KVB, bi ^ 1);
            __builtin_amdgcn_sched_barrier(0);
            asm volatile("s_waitcnt vmcnt(6)" ::: "memory");
        } else {
            asm volatile("s_waitcnt vmcnt(0)" ::: "memory");
        }
        __builtin_amdgcn_sched_barrier(0);
        __builtin_amdgcn_s_barrier();

        // ---- V fragments: direct L2 loads, in flight under QK^T + softmax ----
        bf16x8 vv[4];
#pragma unroll
        for (int t = 0; t < 4; ++t)
            vv[t] = *(const bf16x8*)(vbase + (size_t)(16 * t) * N_ + kv0);
        __builtin_amdgcn_sched_barrier(0);

        // ---- K fragments from LDS (A-operand; rows = k) ----
        const char* khb = (const char*)&khlds[bi][0];
        const char* klb = (const char*)&kllds[bi][0];
        const int ksw = (lr & 7) << 4;
        bf16x8 kh[2][2], kl[2][2];
#pragma unroll
        for (int t = 0; t < 2; ++t) {
            int rb = (16 * t + lr) * 128;
            kh[t][0] = *(const bf16x8*)(khb + rb + ((lg * 16) ^ ksw));
            kh[t][1] = *(const bf16x8*)(khb + rb + ((64 + lg * 16) ^ ksw));
            kl[t][0] = *(const bf16x8*)(klb + rb + ((lg * 16) ^ ksw));
            kl[t][1] = *(const bf16x8*)(klb + rb + ((64 + lg * 16) ^ ksw));
        }

        // ---- S^T = K Q^T (hi/lo split): z[t][r] = S^T[kv0+16t+4lg+r][q0+lr] ----
        f32x4 z[2];
#pragma unroll
        for (int t = 0; t < 2; ++t) {
            f32x4 zz = {};
            zz = MFMA16(kh[t][0], qh0, zz, 0, 0, 0);
            zz = MFMA16(kh[t][1], qh1, zz, 0, 0, 0);
            zz = MFMA16(kh[t][0], ql0, zz, 0, 0, 0);
            zz = MFMA16(kh[t][1], ql1, zz, 0, 0, 0);
            zz = MFMA16(kl[t][0], qh0, zz, 0, 0, 0);
            zz = MFMA16(kl[t][1], qh1, zz, 0, 0, 0);
            z[t] = zz;
        }

        // ---- masks: vectorized f32x4 LDS reads (swizzled) ----
        const float* at = &mlds[w][bi][0][0];
        const float* mt = &mlds[w][bi][1][0];
        f32x4 ma[2], mm[2];
#pragma unroll
        for (int t = 0; t < 2; ++t) {
            int woff = lr * 32 + ((16 * t + 4 * lg) ^ ((lr & 7) << 2));
            ma[t] = *(const f32x4*)(at + woff);
            mm[t] = *(const f32x4*)(mt + woff);
        }

        float sv[2][4];
#pragma unroll
        for (int t = 0; t < 2; ++t)
#pragma unroll
            for (int r = 0; r < 4; ++r)
                sv[t][r] = z[t][r] * rnq + ma[t][r];

        // ---- per-lane online softmax (8 vals + xor16 + xor32) ----
        float vmax = sv[0][0];
#pragma unroll
        for (int t = 0; t < 2; ++t)
#pragma unroll
            for (int r = 0; r < 4; ++r) vmax = fmaxf(vmax, sv[t][r]);
        vmax = fmaxf(vmax, __shfl_xor(vmax, 16));
        vmax = fmaxf(vmax, __shfl_xor(vmax, 32));
        float mn = fmaxf(mrun, vmax);
        float rs = __expf(mrun - mn);
        mrun = mn;
        lrun *= rs;
#pragma unroll
        for (int t = 0; t < 4; ++t) acc[t] *= rs;
        float pe[2][4];
        float rsum = 0.f;
#pragma unroll
        for (int t = 0; t < 2; ++t)
#pragma unroll
            for (int r = 0; r < 4; ++r) { pe[t][r] = __expf(sv[t][r] - mn); rsum += pe[t][r]; }
        rsum += __shfl_xor(rsum, 16);
        rsum += __shfl_xor(rsum, 32);
        lrun += rsum;

        // ---- P_eff -> plds[q=lr][k], vectorized bf16x4 writes ----
#pragma unroll
        for (int t = 0; t < 2; ++t) {
            bf16x4 pk;
#pragma unroll
            for (int r = 0; r < 4; ++r) pk[r] = (bf16)(pe[t][r] * mm[t][r]);
            *(bf16x4*)(pw + lr * 40 + 16 * t + 4 * lg) = pk;
        }

        // ---- B-frag: P[q=lr][8lg..8lg+7]; PV: acc[t'] += V^T x P ----
        bf16x8 pa = *(const bf16x8*)(pw + lr * 40 + 8 * lg);
#pragma unroll
        for (int t = 0; t < 4; ++t)
            acc[t] = MFMA16(vv[t], pa, acc[t], 0, 0, 0);

        __builtin_amdgcn_s_barrier();
    }

    // ---- store unnormalized partials (vectorized) ----
    const size_t cb = ((size_t)c * BH_ + bh) * N_;
    float* ob = &Opart[(cb + q0 + lr) * D_];
#pragma unroll
    for (int t = 0; t < 4; ++t)
        *(f32x4*)(ob + 16 * t + 4 * lg) = acc[t];
    if (lg == 0) {
        Mb[cb + q0 + lr] = mrun;
        Lb[cb + q0 + lr] = lrun;
    }
#undef STAGE
}

// ---------- merge KV-split partials -> normalized attention out (hi/lo bf16) ----------
__global__ __launch_bounds__(256) void merge_kernel(
    const float* __restrict__ Opart, const float* __restrict__ Mb,
    const float* __restrict__ Lb,
    bf16* __restrict__ AOh, bf16* __restrict__ AOl, int ks)
{
    int idx = blockIdx.x * 256 + threadIdx.x;
    int bh = idx >> 14;
    int rem = idx & 16383;
    int q = rem >> 4, d4 = rem & 15;

    float M = -3e38f;
    for (int c = 0; c < ks; ++c)
        M = fmaxf(M, Mb[((size_t)c * BH_ + bh) * N_ + q]);
    float L = 0.f;
    f32x4 o = {};
    for (int c = 0; c < ks; ++c) {
        size_t base = ((size_t)c * BH_ + bh) * N_ + q;
        float wgt = __expf(Mb[base] - M);
        L += wgt * Lb[base];
        f32x4 v = *(const f32x4*)&Opart[base * D_ + d4 * 4];
        o += wgt * v;
    }
    float inv = 1.f / L;
    int b = bh >> 3, h = bh & 7;
    size_t ob = ((size_t)b * N_ + q) * E_ + h * D_ + d4 * 4;
    bf16x4 hi, lo;
#pragma unroll
    for (int j = 0; j < 4; ++j) {
        float x = o[j] * inv;
        bf16 hh = (bf16)x;
        hi[j] = hh;
        lo[j] = (bf16)(x - (float)hh);
    }
    *(bf16x4*)&AOh[ob] = hi;
    *(bf16x4*)&AOl[ob] = lo;
}

// ---------- output projection with W-tile LDS staging, fp32 out + bias ----------
__global__ __launch_bounds__(256) void out_gemm(
    const bf16* __restrict__ Ah, const bf16* __restrict__ Al,
    const bf16* __restrict__ Wh, const bf16* __restrict__ Wl,
    const float* __restrict__ bias,
    float* __restrict__ out)
{
    __shared__ alignas(16) bf16 wlds[2][2][64 * 32];
    const int e0 = blockIdx.x * 64;
    const int m0 = blockIdx.y * 64;
    const int tid = threadIdx.x;
    const int w = tid >> 6, l = tid & 63, lr = l & 15, lg = l >> 4;

    const int wrow = 16 * w + (l >> 2);
    const int wcol = 8 * ((l & 3) ^ ((l >> 3) & 3));
    const bf16* whsrc = Wh + (size_t)(e0 + wrow) * E_ + wcol;
    const bf16* wlsrc = Wl + (size_t)(e0 + wrow) * E_ + wcol;

#define WSTAGE(k0, bi) do {                               \
        gload16(whsrc + (k0), &wlds[bi][0][w * 512]);     \
        gload16(wlsrc + (k0), &wlds[bi][1][w * 512]);     \
    } while (0)

    WSTAGE(0, 0);

    f32x4 acc[4] = {};
    const bf16* ah_p = &Ah[(size_t)(m0 + w * 16 + lr) * E_];
    const bf16* al_p = &Al[(size_t)(m0 + w * 16 + lr) * E_];

    for (int it = 0; it < 16; ++it) {
        const int k0 = it * 32;
        const int bi = it & 1;
        if (it < 15) {
            WSTAGE(k0 + 32, bi ^ 1);
            __builtin_amdgcn_sched_barrier(0);
            asm volatile("s_waitcnt vmcnt(2)" ::: "memory");
        } else {
            asm volatile("s_waitcnt vmcnt(0)" ::: "memory");
        }
        __builtin_amdgcn_sched_barrier(0);
        __builtin_amdgcn_s_barrier();

        bf16x8 ah = *(const bf16x8*)(ah_p + k0 + lg * 8);
        bf16x8 al = *(const bf16x8*)(al_p + k0 + lg * 8);
        const char* whb = (const char*)&wlds[bi][0][0];
        const char* wlb = (const char*)&wlds[bi][1][0];
        const int wsw = ((lr >> 1) & 3) << 4;
#pragma unroll
        for (int t = 0; t < 4; ++t) {
            int rb = (16 * t + lr) * 64;
            bf16x8 bh = *(const bf16x8*)(whb + rb + ((lg * 16) ^ wsw));
            bf16x8 bl = *(const bf16x8*)(wlb + rb + ((lg * 16) ^ wsw));
            acc[t] = MFMA16(ah, bh, acc[t], 0, 0, 0);
            acc[t] = MFMA16(al, bh, acc[t], 0, 0, 0);
            acc[t] = MFMA16(ah, bl, acc[t], 0, 0, 0);
        }
        __builtin_amdgcn_s_barrier();
    }
#undef WSTAGE

#pragma unroll
    for (int t = 0; t < 4; ++t) {
        float bv = bias[e0 + 16 * t + lr];
#pragma unroll
        for (int r = 0; r < 4; ++r) {
            int m = m0 + w * 16 + lg * 4 + r;
            out[(size_t)m * E_ + e0 + 16 * t + lr] = acc[t][r] + bv;
        }
    }
}

extern "C" void kernel_launch(void* const* d_in, const int* in_sizes, int n_in,
                              void* d_out, int out_size, void* d_ws, size_t ws_size,
                              hipStream_t stream) {
    const float* X = (const float*)d_in[0];
    const float* rn = (const float*)d_in[1];
    const float* addm = (const float*)d_in[2];
    const float* multm = (const float*)d_in[3];
    const float* Wq = (const float*)d_in[4];
    const float* bq = (const float*)d_in[5];
    const float* Wk = (const float*)d_in[6];
    const float* bk = (const float*)d_in[7];
    const float* Wv = (const float*)d_in[8];
    const float* bv = (const float*)d_in[9];
    const float* Wo = (const float*)d_in[10];
    const float* bo = (const float*)d_in[11];
    float* out = (float*)d_out;

    const size_t SZ_X = (size_t)B_ * N_ * E_;
    const size_t SZ_W = (size_t)E_ * E_;

    bf16* p = (bf16*)d_ws;
    bf16* Xh = p;  p += SZ_X;
    bf16* Xl = p;  p += SZ_X;
    bf16* Wqh = p; p += SZ_W;
    bf16* Wql = p; p += SZ_W;
    bf16* Wkh = p; p += SZ_W;
    bf16* Wkl = p; p += SZ_W;
    bf16* Wvh = p; p += SZ_W;
    bf16* Woh = p; p += SZ_W;
    bf16* Wol = p; p += SZ_W;
    bf16* Qh = p;  p += SZ_X;
    bf16* Ql = p;  p += SZ_X;
    bf16* Kh = p;  p += SZ_X;
    bf16* Kl = p;  p += SZ_X;
    bf16* Vt = p;  p += SZ_X;
    bf16* AOh = p; p += SZ_X;
    bf16* AOl = p; p += SZ_X;

    size_t fixed_bytes = (size_t)((char*)p - (char*)d_ws);
    size_t per_ks = (size_t)BH_ * N_ * D_ * 4 + (size_t)BH_ * N_ * 2 * 4;
    int ks = 4;
    if (fixed_bytes + 4 * per_ks > ws_size) ks = 2;
    if (fixed_bytes + 2 * per_ks > ws_size) ks = 1;

    float* Opart = (float*)p;
    float* Mb = Opart + (size_t)ks * BH_ * N_ * D_;
    float* Lb = Mb + (size_t)ks * BH_ * N_;

    const int NPREP = B_ * N_ * E_ + 4 * E_ * E_;
    prep_all<<<dim3(NPREP / 256), 256, 0, stream>>>(X, Wq, Wk, Wv, Wo,
        Xh, Xl, Wqh, Wql, Wkh, Wkl, Wvh, Woh, Wol);

    dim3 gq(E_ / 64, (B_ * N_) / 64, 3);
    qkv_gemm<<<gq, 256, 0, stream>>>(Xh, Xl, Wqh, Wql, bq, Wkh, Wkl, bk, Wvh, bv,
                                     Qh, Ql, Kh, Kl, Vt);

    attn_kernel<<<dim3(N_ / 64, ks * BH_), 256, 0, stream>>>(
        Qh, Ql, Kh, Kl, Vt, rn, addm, multm, Opart, Mb, Lb, N_ / ks);

    merge_kernel<<<dim3((BH_ * N_ * (D_ / 4)) / 256), 256, 0, stream>>>(
        Opart, Mb, Lb, AOh, AOl, ks);

    dim3 gg(E_ / 64, (B_ * N_) / 64);
    out_gemm<<<gg, 256, 0, stream>>>(AOh, AOl, Woh, Wol, bo, out);
}

// Round 7
// 146.273 us; speedup vs baseline: 2.1108x; 1.0764x over previous
//
#include <hip/hip_runtime.h>

#define B_ 4
#define N_ 1024
#define E_ 512
#define H_ 8
#define D_ 64
#define BH_ 32
#define KVB 32

typedef __bf16 bf16;
typedef __bf16 bf16x8 __attribute__((ext_vector_type(8)));
typedef __bf16 bf16x4 __attribute__((ext_vector_type(4)));
typedef float f32x4 __attribute__((ext_vector_type(4)));

#define MFMA16 __builtin_amdgcn_mfma_f32_16x16x32_bf16

typedef const __attribute__((address_space(1))) void* gas_t;
typedef __attribute__((address_space(3))) void* las_t;

__device__ __forceinline__ void gload16(const void* g, void* l) {
    __builtin_amdgcn_global_load_lds((gas_t)g, (las_t)l, 16, 0, 0);
}

// ---------- prep: all fp32 -> bf16 hi/lo conversions in one launch ----------
__global__ __launch_bounds__(256) void prep_all(
    const float* __restrict__ X, const float* __restrict__ Wq,
    const float* __restrict__ Wk, const float* __restrict__ Wv,
    const float* __restrict__ Wo,
    bf16* __restrict__ Xh, bf16* __restrict__ Xl,
    bf16* __restrict__ Wqh, bf16* __restrict__ Wql,
    bf16* __restrict__ Wkh, bf16* __restrict__ Wkl,
    bf16* __restrict__ Wvh,
    bf16* __restrict__ Woh, bf16* __restrict__ Wol)
{
    const int NX = B_ * N_ * E_;
    const int NW = E_ * E_;
    int i = blockIdx.x * 256 + threadIdx.x;
    if (i < NX) {
        float x = X[i]; bf16 h = (bf16)x;
        Xh[i] = h; Xl[i] = (bf16)(x - (float)h);
        return;
    }
    i -= NX;
    int w = i >> 18, j = i & (NW - 1);
    if (w == 0) { float x = Wq[j]; bf16 h = (bf16)x; Wqh[j] = h; Wql[j] = (bf16)(x - (float)h); }
    else if (w == 1) { float x = Wk[j]; bf16 h = (bf16)x; Wkh[j] = h; Wkl[j] = (bf16)(x - (float)h); }
    else if (w == 2) { float x = Wv[j]; Wvh[j] = (bf16)x; }
    else if (w == 3) { float x = Wo[j]; bf16 h = (bf16)x; Woh[j] = h; Wol[j] = (bf16)(x - (float)h); }
}

// ---------- fused QKV projection with W-tile LDS staging ----------
// z=0 -> Q (hi/lo out), z=1 -> K (hi/lo out), z=2 -> V^T
__global__ __launch_bounds__(256) void qkv_gemm(
    const bf16* __restrict__ Xh, const bf16* __restrict__ Xl,
    const bf16* __restrict__ Wqh, const bf16* __restrict__ Wql, const float* __restrict__ bq,
    const bf16* __restrict__ Wkh, const bf16* __restrict__ Wkl, const float* __restrict__ bk,
    const bf16* __restrict__ Wvh, const float* __restrict__ bvv,
    bf16* __restrict__ Qh, bf16* __restrict__ Ql,
    bf16* __restrict__ Kh, bf16* __restrict__ Kl,
    bf16* __restrict__ Vt)
{
    __shared__ alignas(16) bf16 wlds[2][2][64 * 32];
    __shared__ alignas(16) bf16 tlds[64 * 72];
    const int z = blockIdx.z;
    const int e0 = blockIdx.x * 64;
    const int m0 = blockIdx.y * 64;
    const int tid = threadIdx.x;
    const int w = tid >> 6, l = tid & 63, lr = l & 15, lg = l >> 4;
    const int h = e0 >> 6;
    const bool three = (z != 2);

    const bf16* Wh = (z == 0) ? Wqh : ((z == 1) ? Wkh : Wvh);
    const bf16* Wl = (z == 0) ? Wql : ((z == 1) ? Wkl : Wqh /*unused*/);

    const int wrow = 16 * w + (l >> 2);
    const int wcol = 8 * ((l & 3) ^ ((l >> 3) & 3));
    const bf16* whsrc = Wh + (size_t)(e0 + wrow) * E_ + wcol;
    const bf16* wlsrc = Wl + (size_t)(e0 + wrow) * E_ + wcol;

#define WSTAGE(k0, bi) do {                                  \
        gload16(whsrc + (k0), &wlds[bi][0][w * 512]);        \
        if (three) gload16(wlsrc + (k0), &wlds[bi][1][w * 512]); \
    } while (0)

    WSTAGE(0, 0);

    f32x4 acc[4] = {};
    const bf16* xh = &Xh[(size_t)(m0 + w * 16 + lr) * E_];
    const bf16* xl = &Xl[(size_t)(m0 + w * 16 + lr) * E_];

    for (int it = 0; it < 16; ++it) {
        const int k0 = it * 32;
        const int bi = it & 1;
        if (it < 15) {
            WSTAGE(k0 + 32, bi ^ 1);
            __builtin_amdgcn_sched_barrier(0);
            if (three) asm volatile("s_waitcnt vmcnt(2)" ::: "memory");
            else       asm volatile("s_waitcnt vmcnt(1)" ::: "memory");
        } else {
            asm volatile("s_waitcnt vmcnt(0)" ::: "memory");
        }
        __builtin_amdgcn_sched_barrier(0);
        __builtin_amdgcn_s_barrier();

        bf16x8 ah = *(const bf16x8*)(xh + k0 + lg * 8);
        bf16x8 al = three ? *(const bf16x8*)(xl + k0 + lg * 8) : ah;

        const char* whb = (const char*)&wlds[bi][0][0];
        const char* wlb = (const char*)&wlds[bi][1][0];
        const int wsw = ((lr >> 1) & 3) << 4;
#pragma unroll
        for (int t = 0; t < 4; ++t) {
            int rb = (16 * t + lr) * 64;
            bf16x8 bh = *(const bf16x8*)(whb + rb + ((lg * 16) ^ wsw));
            acc[t] = MFMA16(ah, bh, acc[t], 0, 0, 0);
            if (three) {
                bf16x8 bl = *(const bf16x8*)(wlb + rb + ((lg * 16) ^ wsw));
                acc[t] = MFMA16(al, bh, acc[t], 0, 0, 0);
                acc[t] = MFMA16(ah, bl, acc[t], 0, 0, 0);
            }
        }
        __builtin_amdgcn_s_barrier();
    }
#undef WSTAGE

    if (z == 2) {
        const float* bias = bvv;
#pragma unroll
        for (int t = 0; t < 4; ++t) {
            float bv = bias[e0 + 16 * t + lr];
#pragma unroll
            for (int r = 0; r < 4; ++r)
                tlds[(16 * t + lr) * 72 + w * 16 + lg * 4 + r] = (bf16)(acc[t][r] + bv);
        }
        __syncthreads();
        int d = tid >> 2, c0 = (tid & 3) * 16;
        int b = m0 >> 10, n = (m0 & (N_ - 1)) + c0;
        bf16x8* dst = (bf16x8*)&Vt[((size_t)(b * H_ + h) * D_ + d) * N_ + n];
        const bf16x8* s = (const bf16x8*)&tlds[d * 72 + c0];
        dst[0] = s[0];
        dst[1] = s[1];
        return;
    }

    const float* bias = z ? bk : bq;
    bf16* Oh = z ? Kh : Qh;
    bf16* Ol = z ? Kl : Ql;
#pragma unroll
    for (int t = 0; t < 4; ++t) {
        float bv = bias[e0 + 16 * t + lr];
#pragma unroll
        for (int r = 0; r < 4; ++r) {
            int m = m0 + w * 16 + lg * 4 + r;
            int b = m >> 10, n = m & (N_ - 1);
            float v = acc[t][r] + bv;
            bf16 hi = (bf16)v;
            size_t idx = ((size_t)(b * H_ + h) * N_ + n) * D_ + 16 * t + lr;
            Oh[idx] = hi;
            Ol[idx] = (bf16)(v - (float)hi);
        }
    }
}

// ---------- fused attention: swapped QK^T, V-first load order (fixed vmcnt) ----------
// Per tile: V[t] loads (4, OLDEST) -> STAGE(t+1) (6) -> vmcnt(10) -> barrier ->
// QK^T/softmax -> vmcnt(6) (V ready, stage still in flight) -> PV -> barrier.
__global__ __launch_bounds__(256) void attn_kernel(
    const bf16* __restrict__ Qh_, const bf16* __restrict__ Ql_,
    const bf16* __restrict__ Kh_, const bf16* __restrict__ Kl_,
    const bf16* __restrict__ Vt_,
    const float* __restrict__ rn,
    const float* __restrict__ addm, const float* __restrict__ multm,
    float* __restrict__ Opart, float* __restrict__ Mb, float* __restrict__ Lb,
    int ch)
{
    __shared__ alignas(16) float mlds[4][2][2][16 * 32];   // 32 KB per-wave mask bufs
    __shared__ alignas(16) bf16 khlds[2][32 * 64];         // 8 KB
    __shared__ alignas(16) bf16 kllds[2][32 * 64];         // 8 KB
    __shared__ alignas(16) bf16 plds[4][16 * 40];          // 5 KB   total 53 KB

    const int by = blockIdx.y;
    const int bh = by & (BH_ - 1), c = by >> 5;
    const int b = bh >> 3;
    const int kvb = c * ch;
    const int tid = threadIdx.x;
    const int w = tid >> 6, l = tid & 63, lr = l & 15, lg = l >> 4;
    const int q0 = blockIdx.x * 64 + w * 16;
    bf16* pw = &plds[w][0];

    const bf16* qb = &Qh_[((size_t)bh * N_ + q0 + lr) * D_];
    const bf16* qlb = &Ql_[((size_t)bh * N_ + q0 + lr) * D_];
    bf16x8 qh0 = *(const bf16x8*)(qb + lg * 8);
    bf16x8 qh1 = *(const bf16x8*)(qb + 32 + lg * 8);
    bf16x8 ql0 = *(const bf16x8*)(qlb + lg * 8);
    bf16x8 ql1 = *(const bf16x8*)(qlb + 32 + lg * 8);

    const float rnq = rn[b * N_ + q0 + lr] * 0.125f;

    float mrun = -3e38f, lrun = 0.f;
    f32x4 acc[4] = {};

    const size_t mb0 = (size_t)bh * N_ * N_;
    const int mrow = l >> 3, mcol = 4 * ((l & 7) ^ ((l >> 3) & 7));
    const float* asrc = addm + mb0 + (size_t)(q0 + mrow) * N_ + mcol;
    const float* msrc = multm + mb0 + (size_t)(q0 + mrow) * N_ + mcol;
    const int krow = 8 * w + (l >> 3), kcol = 8 * ((l & 7) ^ ((l >> 3) & 7));
    const bf16* khsrc = Kh_ + ((size_t)bh * N_ + krow) * D_ + kcol;
    const bf16* klsrc = Kl_ + ((size_t)bh * N_ + krow) * D_ + kcol;
    const bf16* vbase = Vt_ + ((size_t)bh * D_ + lr) * N_ + 8 * lg;

#define STAGE(kv, bi)                                                     \
    do {                                                                  \
        gload16(asrc + (kv), &mlds[w][bi][0][0]);                         \
        gload16(asrc + (kv) + 8 * N_, &mlds[w][bi][0][256]);              \
        gload16(msrc + (kv), &mlds[w][bi][1][0]);                         \
        gload16(msrc + (kv) + 8 * N_, &mlds[w][bi][1][256]);              \
        gload16(khsrc + (size_t)(kv) * D_, &khlds[bi][w * 512]);          \
        gload16(klsrc + (size_t)(kv) * D_, &kllds[bi][w * 512]);          \
    } while (0)

    STAGE(kvb, 0);

    const int nt = ch / KVB;
    for (int tile = 0; tile < nt; ++tile) {
        const int kv0 = kvb + tile * KVB;
        const int bi = tile & 1;

        // ---- V[t] loads FIRST (oldest VMEM ops of this iteration) ----
        bf16x8 vv[4];
#pragma unroll
        for (int t = 0; t < 4; ++t)
            vv[t] = *(const bf16x8*)(vbase + (size_t)(16 * t) * N_ + kv0);
        __builtin_amdgcn_sched_barrier(0);

        // ---- then next-tile STAGE (youngest: stays in flight past all waits) ----
        if (tile + 1 < nt) {
            STAGE(kv0 + KVB, bi ^ 1);
            __builtin_amdgcn_sched_barrier(0);
            asm volatile("s_waitcnt vmcnt(10)" ::: "memory");  // STAGE(t) done; V+STAGE(t+1) in flight
        } else {
            asm volatile("s_waitcnt vmcnt(4)" ::: "memory");   // STAGE(t) done; V in flight
        }
        __builtin_amdgcn_sched_barrier(0);
        __builtin_amdgcn_s_barrier();

        // ---- K fragments from LDS (A-operand; rows = k) ----
        const char* khb = (const char*)&khlds[bi][0];
        const char* klb = (const char*)&kllds[bi][0];
        const int ksw = (lr & 7) << 4;
        bf16x8 kh[2][2], kl[2][2];
#pragma unroll
        for (int t = 0; t < 2; ++t) {
            int rb = (16 * t + lr) * 128;
            kh[t][0] = *(const bf16x8*)(khb + rb + ((lg * 16) ^ ksw));
            kh[t][1] = *(const bf16x8*)(khb + rb + ((64 + lg * 16) ^ ksw));
            kl[t][0] = *(const bf16x8*)(klb + rb + ((lg * 16) ^ ksw));
            kl[t][1] = *(const bf16x8*)(klb + rb + ((64 + lg * 16) ^ ksw));
        }

        // ---- S^T = K Q^T (hi/lo split) ----
        f32x4 z[2];
#pragma unroll
        for (int t = 0; t < 2; ++t) {
            f32x4 zz = {};
            zz = MFMA16(kh[t][0], qh0, zz, 0, 0, 0);
            zz = MFMA16(kh[t][1], qh1, zz, 0, 0, 0);
            zz = MFMA16(kh[t][0], ql0, zz, 0, 0, 0);
            zz = MFMA16(kh[t][1], ql1, zz, 0, 0, 0);
            zz = MFMA16(kl[t][0], qh0, zz, 0, 0, 0);
            zz = MFMA16(kl[t][1], qh1, zz, 0, 0, 0);
            z[t] = zz;
        }

        // ---- masks: vectorized f32x4 LDS reads (swizzled) ----
        const float* at = &mlds[w][bi][0][0];
        const float* mt = &mlds[w][bi][1][0];
        f32x4 ma[2], mm[2];
#pragma unroll
        for (int t = 0; t < 2; ++t) {
            int woff = lr * 32 + ((16 * t + 4 * lg) ^ ((lr & 7) << 2));
            ma[t] = *(const f32x4*)(at + woff);
            mm[t] = *(const f32x4*)(mt + woff);
        }

        float sv[2][4];
#pragma unroll
        for (int t = 0; t < 2; ++t)
#pragma unroll
            for (int r = 0; r < 4; ++r)
                sv[t][r] = z[t][r] * rnq + ma[t][r];

        // ---- per-lane online softmax ----
        float vmax = sv[0][0];
#pragma unroll
        for (int t = 0; t < 2; ++t)
#pragma unroll
            for (int r = 0; r < 4; ++r) vmax = fmaxf(vmax, sv[t][r]);
        vmax = fmaxf(vmax, __shfl_xor(vmax, 16));
        vmax = fmaxf(vmax, __shfl_xor(vmax, 32));
        float mn = fmaxf(mrun, vmax);
        float rs = __expf(mrun - mn);
        mrun = mn;
        lrun *= rs;
#pragma unroll
        for (int t = 0; t < 4; ++t) acc[t] *= rs;
        float pe[2][4];
        float rsum = 0.f;
#pragma unroll
        for (int t = 0; t < 2; ++t)
#pragma unroll
            for (int r = 0; r < 4; ++r) { pe[t][r] = __expf(sv[t][r] - mn); rsum += pe[t][r]; }
        rsum += __shfl_xor(rsum, 16);
        rsum += __shfl_xor(rsum, 32);
        lrun += rsum;

        // ---- P_eff -> plds[q=lr][k] ----
#pragma unroll
        for (int t = 0; t < 2; ++t) {
            bf16x4 pk;
#pragma unroll
            for (int r = 0; r < 4; ++r) pk[r] = (bf16)(pe[t][r] * mm[t][r]);
            *(bf16x4*)(pw + lr * 40 + 16 * t + 4 * lg) = pk;
        }

        // ---- V ready (STAGE(t+1) still in flight); PV ----
        if (tile + 1 < nt) asm volatile("s_waitcnt vmcnt(6)" ::: "memory");
        else               asm volatile("s_waitcnt vmcnt(0)" ::: "memory");
        __builtin_amdgcn_sched_barrier(0);

        bf16x8 pa = *(const bf16x8*)(pw + lr * 40 + 8 * lg);
#pragma unroll
        for (int t = 0; t < 4; ++t)
            acc[t] = MFMA16(vv[t], pa, acc[t], 0, 0, 0);

        __builtin_amdgcn_s_barrier();
    }

    // ---- store unnormalized partials (vectorized) ----
    const size_t cb = ((size_t)c * BH_ + bh) * N_;
    float* ob = &Opart[(cb + q0 + lr) * D_];
#pragma unroll
    for (int t = 0; t < 4; ++t)
        *(f32x4*)(ob + 16 * t + 4 * lg) = acc[t];
    if (lg == 0) {
        Mb[cb + q0 + lr] = mrun;
        Lb[cb + q0 + lr] = lrun;
    }
#undef STAGE
}

// ---------- merge KV-split partials -> normalized attention out (hi/lo bf16) ----------
__global__ __launch_bounds__(256) void merge_kernel(
    const float* __restrict__ Opart, const float* __restrict__ Mb,
    const float* __restrict__ Lb,
    bf16* __restrict__ AOh, bf16* __restrict__ AOl, int ks)
{
    int idx = blockIdx.x * 256 + threadIdx.x;
    int bh = idx >> 14;
    int rem = idx & 16383;
    int q = rem >> 4, d4 = rem & 15;

    float M = -3e38f;
    for (int c = 0; c < ks; ++c)
        M = fmaxf(M, Mb[((size_t)c * BH_ + bh) * N_ + q]);
    float L = 0.f;
    f32x4 o = {};
    for (int c = 0; c < ks; ++c) {
        size_t base = ((size_t)c * BH_ + bh) * N_ + q;
        float wgt = __expf(Mb[base] - M);
        L += wgt * Lb[base];
        f32x4 v = *(const f32x4*)&Opart[base * D_ + d4 * 4];
        o += wgt * v;
    }
    float inv = 1.f / L;
    int b = bh >> 3, h = bh & 7;
    size_t ob = ((size_t)b * N_ + q) * E_ + h * D_ + d4 * 4;
    bf16x4 hi, lo;
#pragma unroll
    for (int j = 0; j < 4; ++j) {
        float x = o[j] * inv;
        bf16 hh = (bf16)x;
        hi[j] = hh;
        lo[j] = (bf16)(x - (float)hh);
    }
    *(bf16x4*)&AOh[ob] = hi;
    *(bf16x4*)&AOl[ob] = lo;
}

// ---------- output projection with W-tile LDS staging, fp32 out + bias ----------
__global__ __launch_bounds__(256) void out_gemm(
    const bf16* __restrict__ Ah, const bf16* __restrict__ Al,
    const bf16* __restrict__ Wh, const bf16* __restrict__ Wl,
    const float* __restrict__ bias,
    float* __restrict__ out)
{
    __shared__ alignas(16) bf16 wlds[2][2][64 * 32];
    const int e0 = blockIdx.x * 64;
    const int m0 = blockIdx.y * 64;
    const int tid = threadIdx.x;
    const int w = tid >> 6, l = tid & 63, lr = l & 15, lg = l >> 4;

    const int wrow = 16 * w + (l >> 2);
    const int wcol = 8 * ((l & 3) ^ ((l >> 3) & 3));
    const bf16* whsrc = Wh + (size_t)(e0 + wrow) * E_ + wcol;
    const bf16* wlsrc = Wl + (size_t)(e0 + wrow) * E_ + wcol;

#define WSTAGE(k0, bi) do {                               \
        gload16(whsrc + (k0), &wlds[bi][0][w * 512]);     \
        gload16(wlsrc + (k0), &wlds[bi][1][w * 512]);     \
    } while (0)

    WSTAGE(0, 0);

    f32x4 acc[4] = {};
    const bf16* ah_p = &Ah[(size_t)(m0 + w * 16 + lr) * E_];
    const bf16* al_p = &Al[(size_t)(m0 + w * 16 + lr) * E_];

    for (int it = 0; it < 16; ++it) {
        const int k0 = it * 32;
        const int bi = it & 1;
        if (it < 15) {
            WSTAGE(k0 + 32, bi ^ 1);
            __builtin_amdgcn_sched_barrier(0);
            asm volatile("s_waitcnt vmcnt(2)" ::: "memory");
        } else {
            asm volatile("s_waitcnt vmcnt(0)" ::: "memory");
        }
        __builtin_amdgcn_sched_barrier(0);
        __builtin_amdgcn_s_barrier();

        bf16x8 ah = *(const bf16x8*)(ah_p + k0 + lg * 8);
        bf16x8 al = *(const bf16x8*)(al_p + k0 + lg * 8);
        const char* whb = (const char*)&wlds[bi][0][0];
        const char* wlb = (const char*)&wlds[bi][1][0];
        const int wsw = ((lr >> 1) & 3) << 4;
#pragma unroll
        for (int t = 0; t < 4; ++t) {
            int rb = (16 * t + lr) * 64;
            bf16x8 bh = *(const bf16x8*)(whb + rb + ((lg * 16) ^ wsw));
            bf16x8 bl = *(const bf16x8*)(wlb + rb + ((lg * 16) ^ wsw));
            acc[t] = MFMA16(ah, bh, acc[t], 0, 0, 0);
            acc[t] = MFMA16(al, bh, acc[t], 0, 0, 0);
            acc[t] = MFMA16(ah, bl, acc[t], 0, 0, 0);
        }
        __builtin_amdgcn_s_barrier();
    }
#undef WSTAGE

#pragma unroll
    for (int t = 0; t < 4; ++t) {
        float bv = bias[e0 + 16 * t + lr];
#pragma unroll
        for (int r = 0; r < 4; ++r) {
            int m = m0 + w * 16 + lg * 4 + r;
            out[(size_t)m * E_ + e0 + 16 * t + lr] = acc[t][r] + bv;
        }
    }
}

extern "C" void kernel_launch(void* const* d_in, const int* in_sizes, int n_in,
                              void* d_out, int out_size, void* d_ws, size_t ws_size,
                              hipStream_t stream) {
    const float* X = (const float*)d_in[0];
    const float* rn = (const float*)d_in[1];
    const float* addm = (const float*)d_in[2];
    const float* multm = (const float*)d_in[3];
    const float* Wq = (const float*)d_in[4];
    const float* bq = (const float*)d_in[5];
    const float* Wk = (const float*)d_in[6];
    const float* bk = (const float*)d_in[7];
    const float* Wv = (const float*)d_in[8];
    const float* bv = (const float*)d_in[9];
    const float* Wo = (const float*)d_in[10];
    const float* bo = (const float*)d_in[11];
    float* out = (float*)d_out;

    const size_t SZ_X = (size_t)B_ * N_ * E_;
    const size_t SZ_W = (size_t)E_ * E_;

    bf16* p = (bf16*)d_ws;
    bf16* Xh = p;  p += SZ_X;
    bf16* Xl = p;  p += SZ_X;
    bf16* Wqh = p; p += SZ_W;
    bf16* Wql = p; p += SZ_W;
    bf16* Wkh = p; p += SZ_W;
    bf16* Wkl = p; p += SZ_W;
    bf16* Wvh = p; p += SZ_W;
    bf16* Woh = p; p += SZ_W;
    bf16* Wol = p; p += SZ_W;
    bf16* Qh = p;  p += SZ_X;
    bf16* Ql = p;  p += SZ_X;
    bf16* Kh = p;  p += SZ_X;
    bf16* Kl = p;  p += SZ_X;
    bf16* Vt = p;  p += SZ_X;
    bf16* AOh = p; p += SZ_X;
    bf16* AOl = p; p += SZ_X;

    size_t fixed_bytes = (size_t)((char*)p - (char*)d_ws);
    size_t per_ks = (size_t)BH_ * N_ * D_ * 4 + (size_t)BH_ * N_ * 2 * 4;
    int ks = 4;
    if (fixed_bytes + 4 * per_ks > ws_size) ks = 2;
    if (fixed_bytes + 2 * per_ks > ws_size) ks = 1;

    float* Opart = (float*)p;
    float* Mb = Opart + (size_t)ks * BH_ * N_ * D_;
    float* Lb = Mb + (size_t)ks * BH_ * N_;

    const int NPREP = B_ * N_ * E_ + 4 * E_ * E_;
    prep_all<<<dim3(NPREP / 256), 256, 0, stream>>>(X, Wq, Wk, Wv, Wo,
        Xh, Xl, Wqh, Wql, Wkh, Wkl, Wvh, Woh, Wol);

    dim3 gq(E_ / 64, (B_ * N_) / 64, 3);
    qkv_gemm<<<gq, 256, 0, stream>>>(Xh, Xl, Wqh, Wql, bq, Wkh, Wkl, bk, Wvh, bv,
                                     Qh, Ql, Kh, Kl, Vt);

    attn_kernel<<<dim3(N_ / 64, ks * BH_), 256, 0, stream>>>(
        Qh, Ql, Kh, Kl, Vt, rn, addm, multm, Opart, Mb, Lb, N_ / ks);

    merge_kernel<<<dim3((BH_ * N_ * (D_ / 4)) / 256), 256, 0, stream>>>(
        Opart, Mb, Lb, AOh, AOl, ks);

    dim3 gg(E_ / 64, (B_ * N_) / 64);
    out_gemm<<<gg, 256, 0, stream>>>(AOh, AOl, Woh, Wol, bo, out);
}